// Round 16
// baseline (767.095 us; speedup 1.0000x reference)
//
#include <hip/hip_runtime.h>
#include <hip/hip_bf16.h>

// VAE with grid-GCN encoder, MI355X. Round 15: wave-autonomous einsum —
// zero barriers in main loop; each wave owns 32-node chunks + a private
// swizzled LDS region; single end-merge. gcn + tail unchanged.

#define BB 1024
#define HG 28
#define NN 784
#define KK 70
#define F3 48
#define HD 400
#define ZD 70
#define IMGD 784

typedef __hip_bfloat16 bf16;
typedef __attribute__((ext_vector_type(8))) short s8v;
typedef __attribute__((ext_vector_type(4))) float f32x4;

__device__ __forceinline__ float dinv_ij(int i, int j){
  int deg = 1 + (i>0) + (i<HG-1) + (j>0) + (j<HG-1);
  return rsqrtf((float)deg);
}

__device__ __forceinline__ unsigned pk2(float a, float b){
  union { bf16 h; unsigned short u; } ua, ub;
  ua.h = __float2bfloat16(a); ub.h = __float2bfloat16(b);
  return ((unsigned)ub.u << 16) | ua.u;
}

__device__ __forceinline__ short bfbits(float v){
  union { bf16 h; short s; } u; u.h = __float2bfloat16(v); return u.s;
}

// Three GCN layers fused, one block per (sample, 7-row slab). (unchanged)
__global__ __launch_bounds__(256, 2)
void gcn_fused(const float* __restrict__ nodes,
               const float* __restrict__ W1, const float* __restrict__ b1,
               const float* __restrict__ W2, const float* __restrict__ b2,
               const float* __restrict__ W3, const float* __restrict__ b3,
               bf16* __restrict__ h3){
  __shared__ __align__(16) char smem[73216];
  float* regA = (float*)smem;
  float* regB = (float*)(smem + 36288);
  float* wbuf = (float*)(smem + 64512);
  float* W1s = wbuf;          float* b1s = wbuf + 32;
  float* W2s = wbuf + 48;     float* b2s = wbuf + 560;
  float* W3s = wbuf + 592;    float* b3s = wbuf + 2128;

  int tid = threadIdx.x;
  if (tid < 32)  W1s[tid] = W1[tid];
  if (tid < 16)  b1s[tid] = b1[tid];
  for (int t = tid; t < 512;  t += 256) W2s[t] = W2[t];
  if (tid < 32)  b2s[tid] = b2[tid];
  for (int t = tid; t < 1536; t += 256) W3s[t] = W3[t];
  if (tid < 48)  b3s[tid] = b3[tid];

  int b = blockIdx.x >> 2, s = blockIdx.x & 3;
  int base3 = s*7;
  int base2 = base3 - 1;
  int base1 = base3 - 2;
  const float* nb = nodes + (size_t)b*NN*2;
  __syncthreads();

  {
    float* h1s = regA;
    for (int t = tid; t < 308; t += 256){
      int lr = t/28, j = t - lr*28;
      int r = base1 + lr;
      float o[16] __attribute__((aligned(16)));
      if (r < 0 || r >= HG){
        #pragma unroll
        for (int f=0; f<16; f++) o[f] = 0.f;
      } else {
        float dn = dinv_ij(r,j);
        float a0 = dn*nb[(r*HG+j)*2+0], a1 = dn*nb[(r*HG+j)*2+1];
        if (r > 0)   { float w=dinv_ij(r-1,j); a0 += w*nb[((r-1)*HG+j)*2]; a1 += w*nb[((r-1)*HG+j)*2+1]; }
        if (r < HG-1){ float w=dinv_ij(r+1,j); a0 += w*nb[((r+1)*HG+j)*2]; a1 += w*nb[((r+1)*HG+j)*2+1]; }
        if (j > 0)   { float w=dinv_ij(r,j-1); a0 += w*nb[(r*HG+j-1)*2];   a1 += w*nb[(r*HG+j-1)*2+1]; }
        if (j < HG-1){ float w=dinv_ij(r,j+1); a0 += w*nb[(r*HG+j+1)*2];   a1 += w*nb[(r*HG+j+1)*2+1]; }
        a0 *= dn; a1 *= dn;
        #pragma unroll
        for (int f=0; f<16; f++) o[f] = fmaxf(a0*W1s[f] + a1*W1s[16+f] + b1s[f], 0.f);
      }
      float* dst = h1s + t*20;
      #pragma unroll
      for (int qq=0; qq<4; qq++) *(float4*)(dst + 4*qq) = *(float4*)&o[4*qq];
    }
  }
  __syncthreads();

  if (tid < 252){
    const float* h1s = regA;
    float* agg1 = regB;
    int lr = tid/28, j = tid - lr*28;
    int r = base2 + lr;
    float o[16] __attribute__((aligned(16)));
    if (r < 0 || r >= HG){
      #pragma unroll
      for (int f=0; f<16; f++) o[f] = 0.f;
    } else {
      int ln = (lr+1)*28 + j;
      float dn = dinv_ij(r,j);
      float wu = dinv_ij(r-1,j), wd = dinv_ij(r+1,j);
      float wl = (j>0)    ? dinv_ij(r,j-1) : 0.f;
      float wr = (j<HG-1) ? dinv_ij(r,j+1) : 0.f;
      const float* pc = h1s + ln*20;
      #pragma unroll
      for (int qq=0; qq<4; qq++){
        float4 vc = *(const float4*)(pc + 4*qq);
        float4 vu = *(const float4*)(pc - 28*20 + 4*qq);
        float4 vd = *(const float4*)(pc + 28*20 + 4*qq);
        float4 vl = *(const float4*)(pc - 20 + 4*qq);
        float4 vr = *(const float4*)(pc + 20 + 4*qq);
        o[4*qq+0] = dn*(dn*vc.x + wu*vu.x + wd*vd.x + wl*vl.x + wr*vr.x);
        o[4*qq+1] = dn*(dn*vc.y + wu*vu.y + wd*vd.y + wl*vl.y + wr*vr.y);
        o[4*qq+2] = dn*(dn*vc.z + wu*vu.z + wd*vd.z + wl*vl.z + wr*vr.z);
        o[4*qq+3] = dn*(dn*vc.w + wu*vu.w + wd*vd.w + wl*vl.w + wr*vr.w);
      }
    }
    float* dst = agg1 + tid*20;
    #pragma unroll
    for (int qq=0; qq<4; qq++) *(float4*)(dst + 4*qq) = *(float4*)&o[4*qq];
  }
  __syncthreads();

  {
    const float* agg1 = regB;
    float* h2s = regA;
    int tx = tid & 7, ty = tid >> 3;
    float4 w2r[16];
    #pragma unroll
    for (int fi=0; fi<16; fi++) w2r[fi] = *(const float4*)&W2s[fi*32 + tx*4];
    float4 bb = *(const float4*)&b2s[tx*4];
    #pragma unroll
    for (int i=0; i<8; i++){
      int n = ty + 32*i;
      if (n < 252){
        float af[16] __attribute__((aligned(16)));
        const float* ap = agg1 + n*20;
        #pragma unroll
        for (int qq=0; qq<4; qq++) *(float4*)&af[4*qq] = *(const float4*)(ap + 4*qq);
        float4 acc = bb;
        #pragma unroll
        for (int fi=0; fi<16; fi++){
          float a = af[fi];
          acc.x += a*w2r[fi].x; acc.y += a*w2r[fi].y;
          acc.z += a*w2r[fi].z; acc.w += a*w2r[fi].w;
        }
        acc.x = fmaxf(acc.x,0.f); acc.y = fmaxf(acc.y,0.f);
        acc.z = fmaxf(acc.z,0.f); acc.w = fmaxf(acc.w,0.f);
        *(float4*)&h2s[n*36 + tx*4] = acc;
      }
    }
  }
  __syncthreads();

  if (tid < 196){
    const float* h2s = regA;
    float* agg2 = regB;
    int lr = tid/28, j = tid - lr*28;
    int r = base3 + lr;
    int ln = (lr+1)*28 + j;
    float dn = dinv_ij(r,j);
    float wu = dinv_ij(r-1,j), wd = dinv_ij(r+1,j);
    float wl = (j>0)    ? dinv_ij(r,j-1) : 0.f;
    float wr = (j<HG-1) ? dinv_ij(r,j+1) : 0.f;
    const float* pc = h2s + ln*36;
    float* dst = agg2 + tid*36;
    #pragma unroll
    for (int qq=0; qq<8; qq++){
      float4 vc = *(const float4*)(pc + 4*qq);
      float4 vu = *(const float4*)(pc - 28*36 + 4*qq);
      float4 vd = *(const float4*)(pc + 28*36 + 4*qq);
      float4 vl = *(const float4*)(pc - 36 + 4*qq);
      float4 vr = *(const float4*)(pc + 36 + 4*qq);
      float4 o;
      o.x = dn*(dn*vc.x + wu*vu.x + wd*vd.x + wl*vl.x + wr*vr.x);
      o.y = dn*(dn*vc.y + wu*vu.y + wd*vd.y + wl*vl.y + wr*vr.y);
      o.z = dn*(dn*vc.z + wu*vu.z + wd*vd.z + wl*vl.z + wr*vr.z);
      o.w = dn*(dn*vc.w + wu*vu.w + wd*vd.w + wl*vl.w + wr*vr.w);
      *(float4*)(dst + 4*qq) = o;
    }
  }
  __syncthreads();

  {
    bf16* h3buf = (bf16*)regA;
    if (tid < 252){
      const float* agg2 = regB;
      int tx = tid % 12, ty = tid / 12;
      float4 w3r[32];
      #pragma unroll
      for (int fi=0; fi<32; fi++) w3r[fi] = *(const float4*)&W3s[fi*48 + tx*4];
      float4 bb = *(const float4*)&b3s[tx*4];
      #pragma unroll
      for (int i=0; i<10; i++){
        int n = ty + 21*i;
        if (n < 196){
          float af[32] __attribute__((aligned(16)));
          const float* ap = agg2 + n*36;
          #pragma unroll
          for (int qq=0; qq<8; qq++) *(float4*)&af[4*qq] = *(const float4*)(ap + 4*qq);
          float4 acc = bb;
          #pragma unroll
          for (int fi=0; fi<32; fi++){
            float a = af[fi];
            acc.x += a*w3r[fi].x; acc.y += a*w3r[fi].y;
            acc.z += a*w3r[fi].z; acc.w += a*w3r[fi].w;
          }
          uint2 pv;
          pv.x = pk2(fmaxf(acc.x,0.f), fmaxf(acc.y,0.f));
          pv.y = pk2(fmaxf(acc.z,0.f), fmaxf(acc.w,0.f));
          *(uint2*)((char*)h3buf + n*112 + tx*8) = pv;
        }
      }
    }
  }
  __syncthreads();

  {
    const char* h3buf = (const char*)regA;
    uint4* dst = (uint4*)(h3 + ((size_t)b*NN + base3*28)*F3);
    for (int t = tid; t < 1176; t += 256){
      int n = t/6, gq = t - n*6;
      dst[t] = *(const uint4*)(h3buf + n*112 + gq*16);
    }
  }
}

// Wave-autonomous gumbel-softmax + einsum. Block = 1 sample, 4 waves.
// Wave w owns 32-node chunks {w, w+4, ...} of 25; private 13.3KB LDS region
// (XOR-swizzled 4-u32 groups); NO barriers in the main loop.
__global__
void einsum_mfma_kernel(const float* __restrict__ logits, const float* __restrict__ gumbel,
                        const bf16* __restrict__ h3, float* __restrict__ g){
  __shared__ __align__(16) unsigned smemS[13312];   // 4 waves x 3328 u32 = 53,248 B

  int b = blockIdx.x, tid = threadIdx.x;
  int l = tid & 63, w = tid >> 6;
  unsigned* st  = smemS + w*3328;    // hi  [80][16] u32 (node-pair packed)
  unsigned* stl = st + 1280;         // lo  [80][16]
  unsigned* ht  = st + 2560;         // ht  [48][16]

  // zero pad k-rows 70..79 of own region (hi+lo)
  for (int t = l; t < 160; t += 64){ st[1120 + t] = 0u; stl[1120 + t] = 0u; }

  f32x4 acc[5][3];
  #pragma unroll
  for (int mt=0; mt<5; mt++)
    #pragma unroll
    for (int bt=0; bt<3; bt++) acc[mt][bt] = (f32x4){0.f,0.f,0.f,0.f};

  int node_l = l >> 1;          // chunk-local node 0..31
  int half = l & 1;             // k-half: 0 -> k0..34, 1 -> k35..69
  int pairm = l >> 2;           // node-pair 0..15
  int nodehalf = (l >> 1) & 1;  // even/odd node of pair
  int hm = l & 15, hq = l >> 4; // ht loader: pair, f-quad(12 wide)

  for (int c = w; c < 25; c += 4){
    int c0 = c*32;
    int n = c0 + node_l;
    bool v = n < NN;
    // ---- uniform 18x float2 loads per pointer (overlap-discard at the 35-split)
    const float* lp = logits + ((size_t)b*NN + n)*KK;
    const float* gp = gumbel + ((size_t)b*NN + n)*KK;
    int kbase = half ? 34 : 0;   // 8B-aligned for both halves
    float x[35];
    {
      float2 lv[18], gv[18];
      #pragma unroll
      for (int s=0; s<18; s++){
        lv[s] = v ? *(const float2*)(lp + kbase + 2*s) : (float2){0.f,0.f};
        gv[s] = v ? *(const float2*)(gp + kbase + 2*s) : (float2){0.f,0.f};
      }
      if (half == 0){
        #pragma unroll
        for (int i=0; i<35; i++){
          int s = i >> 1;
          x[i] = (i & 1) ? 2.f*(lv[s].y + gv[s].y) : 2.f*(lv[s].x + gv[s].x);
        }
      } else {
        x[0] = 2.f*(lv[0].y + gv[0].y);               // k35
        #pragma unroll
        for (int i=1; i<35; i++){
          int s = (i + 1) >> 1;
          x[i] = (i & 1) ? 2.f*(lv[s].x + gv[s].x) : 2.f*(lv[s].y + gv[s].y);
        }
      }
    }
    // ---- softmax across the lane pair (l, l^1)
    float mx = -1e30f;
    #pragma unroll
    for (int i=0; i<35; i++) mx = fmaxf(mx, x[i]);
    mx = fmaxf(mx, __shfl_xor(mx, 1));
    float sum = 0.f;
    #pragma unroll
    for (int i=0; i<35; i++){ x[i] = __expf(x[i]-mx); sum += x[i]; }
    sum += __shfl_xor(sum, 1);
    float rs = v ? 1.0f/sum : 0.f;
    // ---- pack to st/stl (node-pair u32 via shfl(2)); swizzled group
    #pragma unroll
    for (int i=0; i<35; i++){
      float p = x[i]*rs;
      unsigned hb = (unsigned)(unsigned short)bfbits(p);
      union { short s; bf16 h; } uh; uh.s = (short)hb;
      float lo = p - __bfloat162float(uh.h);
      unsigned lb = (unsigned)(unsigned short)bfbits(lo);
      unsigned phb = (unsigned)__shfl_xor((int)hb, 2);
      unsigned plb = (unsigned)__shfl_xor((int)lb, 2);
      unsigned dh = (nodehalf==0) ? (hb | (phb<<16)) : (phb | (hb<<16));
      unsigned dl = (nodehalf==0) ? (lb | (plb<<16)) : (plb | (lb<<16));
      bool doW = (nodehalf==0) ? (i < 18) : (i >= 18);
      if (doW){
        int k = half*35 + i;
        int grp = (pairm >> 2) ^ ((k >> 1) & 3);
        int col = grp*4 + (pairm & 3);
        st[k*16 + col] = dh;
        stl[k*16 + col] = dl;
      }
    }
    // ---- ht transpose-pack: lane (hm,hq) handles f = hq*12 .. hq*12+11
    {
      int nA = c0 + 2*hm, nB = nA + 1;
      bool vA = nA < NN, vB = nB < NN;
      const bf16* pA = h3 + ((size_t)b*NN + nA)*F3 + hq*12;
      const bf16* pB = h3 + ((size_t)b*NN + nB)*F3 + hq*12;
      #pragma unroll
      for (int j=0; j<3; j++){
        uint2 uA = vA ? *(const uint2*)(pA + 4*j) : (uint2){0u,0u};
        uint2 uB = vB ? *(const uint2*)(pB + 4*j) : (uint2){0u,0u};
        int f0 = hq*12 + 4*j;
        unsigned dv[4];
        dv[0] = (uA.x & 0xFFFFu) | (uB.x << 16);
        dv[1] = (uA.x >> 16)     | (uB.x & 0xFFFF0000u);
        dv[2] = (uA.y & 0xFFFFu) | (uB.y << 16);
        dv[3] = (uA.y >> 16)     | (uB.y & 0xFFFF0000u);
        #pragma unroll
        for (int i2=0; i2<4; i2++){
          int f = f0 + i2;
          int grp = (hm >> 2) ^ ((f >> 1) & 3);
          int col = grp*4 + (hm & 3);
          ht[f*16 + col] = dv[i2];
        }
      }
    }
    // ---- MFMA (same-wave LDS; compiler inserts lgkmcnt waits, no barrier)
    {
      int lo4 = (l & 15) >> 1;
      int grp = (l >> 4) ^ (lo4 & 3);        // same for A and B rows (row%16 = l&15)
      s8v Bf[3];
      #pragma unroll
      for (int bt=0; bt<3; bt++){
        int fb = bt*16 + (l & 15);
        Bf[bt] = *(const s8v*)&ht[fb*16 + grp*4];
      }
      #pragma unroll
      for (int mt=0; mt<5; mt++){
        int row = mt*16 + (l & 15);
        s8v Af = *(const s8v*)&st[row*16 + grp*4];
        s8v Al = *(const s8v*)&stl[row*16 + grp*4];
        #pragma unroll
        for (int bt=0; bt<3; bt++){
          acc[mt][bt] = __builtin_amdgcn_mfma_f32_16x16x32_bf16(Af, Bf[bt], acc[mt][bt], 0, 0, 0);
          acc[mt][bt] = __builtin_amdgcn_mfma_f32_16x16x32_bf16(Al, Bf[bt], acc[mt][bt], 0, 0, 0);
        }
      }
    }
  }

  // ---- cross-wave merge (only sync point) ----
  __syncthreads();
  float* cred = (float*)smemS;   // [80][49], 15,680 B (wave regions dead)
  for (int rw = 0; rw < 4; rw++){
    if (w == rw){
      #pragma unroll
      for (int mt=0; mt<5; mt++)
        #pragma unroll
        for (int bt=0; bt<3; bt++)
          #pragma unroll
          for (int r=0; r<4; r++){
            int row = mt*16 + (l>>4)*4 + r;
            int col = bt*16 + (l&15);
            if (rw == 0) cred[row*49 + col] = acc[mt][bt][r];
            else         cred[row*49 + col] += acc[mt][bt][r];
          }
    }
    __syncthreads();
  }
  for (int t = tid; t < KK*F3; t += 256){
    int r = t / F3, c2 = t - r*F3;
    g[(size_t)b*(KK*F3) + t] = cred[r*49 + c2];
  }
}

// Register-prefetch dense: out = act(A @ W + b). ACT: 0=relu,1=sigmoid,2=partial.
template<int ACT>
__global__ __launch_bounds__(256)
void dense_kernel(const float* __restrict__ A, const float* __restrict__ W,
                  const float* __restrict__ bias, float* __restrict__ out,
                  int M, int K, int Nn, int kChunk){
  __shared__ float As[16][65];
  __shared__ float Bs[16][64];
  int tx = threadIdx.x & 15, ty = threadIdx.x >> 4;
  int m0 = blockIdx.x*64, n0 = blockIdx.y*64;
  int ks = blockIdx.z * kChunk;
  int ke = min(K, ks + kChunk);
  int a_kk = threadIdx.x & 15, a_mm = threadIdx.x >> 4;
  int b_nn = threadIdx.x & 63, b_k0 = threadIdx.x >> 6;
  float ra[4], rb[4];
  float acc[4][4] = {};

  #pragma unroll
  for (int s=0; s<4; s++){
    int gk = ks + a_kk;
    ra[s] = (gk < ke) ? A[(size_t)(m0 + a_mm + s*16)*K + gk] : 0.f;
  }
  #pragma unroll
  for (int s=0; s<4; s++){
    int gk = ks + b_k0 + s*4, gn = n0 + b_nn;
    rb[s] = (gk < ke && gn < Nn) ? W[(size_t)gk*Nn + gn] : 0.f;
  }

  for (int k0 = ks; k0 < ke; k0 += 16){
    #pragma unroll
    for (int s=0; s<4; s++) As[a_kk][a_mm + s*16] = ra[s];
    #pragma unroll
    for (int s=0; s<4; s++) Bs[b_k0 + s*4][b_nn] = rb[s];
    __syncthreads();
    if (k0 + 16 < ke){
      #pragma unroll
      for (int s=0; s<4; s++){
        int gk = k0 + 16 + a_kk;
        ra[s] = (gk < ke) ? A[(size_t)(m0 + a_mm + s*16)*K + gk] : 0.f;
      }
      #pragma unroll
      for (int s=0; s<4; s++){
        int gk = k0 + 16 + b_k0 + s*4, gn = n0 + b_nn;
        rb[s] = (gk < ke && gn < Nn) ? W[(size_t)gk*Nn + gn] : 0.f;
      }
    }
    #pragma unroll
    for (int kk=0; kk<16; kk++){
      float a[4], bv[4];
      #pragma unroll
      for (int i2=0; i2<4; i2++) a[i2] = As[kk][ty*4+i2];
      #pragma unroll
      for (int j2=0; j2<4; j2++) bv[j2] = Bs[kk][tx*4+j2];
      #pragma unroll
      for (int i2=0; i2<4; i2++)
        #pragma unroll
        for (int j2=0; j2<4; j2++) acc[i2][j2] += a[i2]*bv[j2];
    }
    __syncthreads();
  }

  if (ACT == 2){
    float* po = out + (size_t)blockIdx.z*M*Nn;
    #pragma unroll
    for (int j2=0; j2<4; j2++){
      int gn = n0 + tx*4 + j2;
      if (gn < Nn){
        #pragma unroll
        for (int i2=0; i2<4; i2++)
          po[(size_t)(m0 + ty*4 + i2)*Nn + gn] = acc[i2][j2];
      }
    }
  } else {
    #pragma unroll
    for (int j2=0; j2<4; j2++){
      int gn = n0 + tx*4 + j2;
      if (gn < Nn){
        float bb = bias[gn];
        #pragma unroll
        for (int i2=0; i2<4; i2++){
          float v = acc[i2][j2] + bb;
          v = (ACT == 0) ? fmaxf(v, 0.f) : 1.0f/(1.0f + __expf(-v));
          out[(size_t)(m0 + ty*4 + i2)*Nn + gn] = v;
        }
      }
    }
  }
}

// dual-B partial: B column gn<70 from Wmu, else Wvar
__global__ __launch_bounds__(256)
void dense_dualB_partial(const float* __restrict__ A, const float* __restrict__ Wmu,
                         const float* __restrict__ Wvar, float* __restrict__ out,
                         int M, int K, int Nn, int kChunk){
  __shared__ float As[16][65];
  __shared__ float Bs[16][64];
  int tx = threadIdx.x & 15, ty = threadIdx.x >> 4;
  int m0 = blockIdx.x*64, n0 = blockIdx.y*64;
  int ks = blockIdx.z * kChunk;
  int ke = min(K, ks + kChunk);
  int a_kk = threadIdx.x & 15, a_mm = threadIdx.x >> 4;
  int b_nn = threadIdx.x & 63, b_k0 = threadIdx.x >> 6;
  float ra[4], rb[4];
  float acc[4][4] = {};

  auto bload = [&](int gk, int gn)->float{
    if (gk >= ke || gn >= Nn) return 0.f;
    return (gn < ZD) ? Wmu[(size_t)gk*ZD + gn] : Wvar[(size_t)gk*ZD + gn - ZD];
  };

  #pragma unroll
  for (int s=0; s<4; s++){
    int gk = ks + a_kk;
    ra[s] = (gk < ke) ? A[(size_t)(m0 + a_mm + s*16)*K + gk] : 0.f;
  }
  #pragma unroll
  for (int s=0; s<4; s++) rb[s] = bload(ks + b_k0 + s*4, n0 + b_nn);

  for (int k0 = ks; k0 < ke; k0 += 16){
    #pragma unroll
    for (int s=0; s<4; s++) As[a_kk][a_mm + s*16] = ra[s];
    #pragma unroll
    for (int s=0; s<4; s++) Bs[b_k0 + s*4][b_nn] = rb[s];
    __syncthreads();
    if (k0 + 16 < ke){
      #pragma unroll
      for (int s=0; s<4; s++){
        int gk = k0 + 16 + a_kk;
        ra[s] = (gk < ke) ? A[(size_t)(m0 + a_mm + s*16)*K + gk] : 0.f;
      }
      #pragma unroll
      for (int s=0; s<4; s++) rb[s] = bload(k0 + 16 + b_k0 + s*4, n0 + b_nn);
    }
    #pragma unroll
    for (int kk=0; kk<16; kk++){
      float a[4], bv[4];
      #pragma unroll
      for (int i2=0; i2<4; i2++) a[i2] = As[kk][ty*4+i2];
      #pragma unroll
      for (int j2=0; j2<4; j2++) bv[j2] = Bs[kk][tx*4+j2];
      #pragma unroll
      for (int i2=0; i2<4; i2++)
        #pragma unroll
        for (int j2=0; j2<4; j2++) acc[i2][j2] += a[i2]*bv[j2];
    }
    __syncthreads();
  }

  float* po = out + (size_t)blockIdx.z*M*Nn;
  #pragma unroll
  for (int j2=0; j2<4; j2++){
    int gn = n0 + tx*4 + j2;
    if (gn < Nn){
      #pragma unroll
      for (int i2=0; i2<4; i2++)
        po[(size_t)(m0 + ty*4 + i2)*Nn + gn] = acc[i2][j2];
    }
  }
}

// split-K partial reduction + bias + activation (0=relu, 1=sigmoid)
template<int ACT>
__global__ __launch_bounds__(256)
void reduce_bias_act(const float* __restrict__ part, const float* __restrict__ bias,
                     float* __restrict__ out, int M, int Nn, int S){
  int idx = blockIdx.x*256 + threadIdx.x;
  if (idx >= M*Nn) return;
  int n = idx % Nn;
  float s = bias[n];
  for (int i=0; i<S; i++) s += part[(size_t)i*M*Nn + idx];
  out[idx] = (ACT == 0) ? fmaxf(s, 0.f) : 1.0f/(1.0f + __expf(-s));
}

// reduce mu|var partials + reparameterize
__global__ __launch_bounds__(256)
void reduce_reparam(const float* __restrict__ part, const float* __restrict__ bmu,
                    const float* __restrict__ bvar, const float* __restrict__ eps,
                    float* __restrict__ z, int S){
  int idx = blockIdx.x*256 + threadIdx.x;
  int b = idx / ZD, zi = idx - b*ZD;
  float mu = bmu[zi], va = bvar[zi];
  for (int s=0; s<S; s++){
    const float* pr = part + ((size_t)s*BB + b)*140;
    mu += pr[zi];
    va += pr[ZD + zi];
  }
  float sp = fmaxf(va, 0.f) + log1pf(__expf(-fabsf(va)));
  z[idx] = mu + eps[idx]*sqrtf(sp + 1e-10f);
}

extern "C" void kernel_launch(void* const* d_in, const int* in_sizes, int n_in,
                              void* d_out, int out_size, void* d_ws, size_t ws_size,
                              hipStream_t stream){
  (void)in_sizes; (void)n_in; (void)out_size; (void)ws_size;
  const float* nodes  = (const float*)d_in[0];
  const float* logits = (const float*)d_in[1];
  const float* gumbel = (const float*)d_in[2];
  const float* eps    = (const float*)d_in[3];
  const float* W1 =(const float*)d_in[4],  *b1 =(const float*)d_in[5];
  const float* W2 =(const float*)d_in[6],  *b2 =(const float*)d_in[7];
  const float* W3 =(const float*)d_in[8],  *b3 =(const float*)d_in[9];
  const float* We1=(const float*)d_in[10], *be1=(const float*)d_in[11];
  const float* We2=(const float*)d_in[12], *be2=(const float*)d_in[13];
  const float* Wmu=(const float*)d_in[14], *bmu=(const float*)d_in[15];
  const float* Wvr=(const float*)d_in[16], *bvr=(const float*)d_in[17];
  const float* Wd1=(const float*)d_in[18], *bd1=(const float*)d_in[19];
  const float* Wd2=(const float*)d_in[20], *bd2=(const float*)d_in[21];

  char* ws = (char*)d_ws;
  bf16*  h3 = (bf16*)(ws);                 // 77,070,336 B
  float* g  = (float*)(ws + 77070336);     // 13,762,560 B
  float* e1 = (float*)(ws + 90832896);
  float* e2 = (float*)(ws + 92471296);
  float* zb = (float*)(ws + 94109696);
  float* dd = (float*)(ws + 94396416);
  float* part = (float*)(ws);              // aliases h3 (dead after einsum)
  float* out = (float*)d_out;

  gcn_fused<<<4096, 256, 0, stream>>>(nodes, W1, b1, W2, b2, W3, b3, h3);
  einsum_mfma_kernel<<<1024, 256, 0, stream>>>(logits, gumbel, h3, g);
  dense_kernel<2><<<dim3(16, 7, 8), 256, 0, stream>>>(g, We1, nullptr, part, 1024, 3360, 400, 432);
  reduce_bias_act<0><<<1600, 256, 0, stream>>>(part, be1, e1, 1024, 400, 8);
  dense_kernel<2><<<dim3(16, 7, 4), 256, 0, stream>>>(e1, We2, nullptr, part, 1024, 400, 400, 112);
  reduce_bias_act<0><<<1600, 256, 0, stream>>>(part, be2, e2, 1024, 400, 4);
  dense_dualB_partial<<<dim3(16, 3, 4), 256, 0, stream>>>(e2, Wmu, Wvr, part, 1024, 400, 140, 112);
  reduce_reparam<<<280, 256, 0, stream>>>(part, bmu, bvr, eps, zb, 4);
  dense_kernel<0><<<dim3(16, 7, 1), 256, 0, stream>>>(zb, Wd1, bd1, dd, 1024, 70, 400, 70);
  dense_kernel<2><<<dim3(16, 13, 4), 256, 0, stream>>>(dd, Wd2, nullptr, part, 1024, 400, 784, 112);
  reduce_bias_act<1><<<3136, 256, 0, stream>>>(part, bd2, out, 1024, 784, 4);
}

// Round 17
// 493.609 us; speedup vs baseline: 1.5541x; 1.5541x over previous
//
#include <hip/hip_runtime.h>
#include <hip/hip_bf16.h>

// VAE with grid-GCN encoder, MI355X. Round 16: einsum reverted to r15-exact
// (best clean: 193us); mid-tail (We2 -> mu/var -> reparam -> Wd1) fused into
// one encoder_tail kernel (4 rows/block, 256 blocks, f32 exact).

#define BB 1024
#define HG 28
#define NN 784
#define KK 70
#define F3 48
#define HD 400
#define ZD 70
#define IMGD 784

typedef __hip_bfloat16 bf16;
typedef __attribute__((ext_vector_type(8))) short s8v;
typedef __attribute__((ext_vector_type(4))) float f32x4;

__device__ __forceinline__ float dinv_ij(int i, int j){
  int deg = 1 + (i>0) + (i<HG-1) + (j>0) + (j<HG-1);
  return rsqrtf((float)deg);
}

__device__ __forceinline__ unsigned pk2(float a, float b){
  union { bf16 h; unsigned short u; } ua, ub;
  ua.h = __float2bfloat16(a); ub.h = __float2bfloat16(b);
  return ((unsigned)ub.u << 16) | ua.u;
}

__device__ __forceinline__ short bfbits(float v){
  union { bf16 h; short s; } u; u.h = __float2bfloat16(v); return u.s;
}

// LDS-visibility barrier WITHOUT vmcnt drain.
#define SYNC_LDS() do {                                   \
    asm volatile("" ::: "memory");                        \
    asm volatile("s_waitcnt lgkmcnt(0)" ::: "memory");    \
    __builtin_amdgcn_s_barrier();                         \
    asm volatile("" ::: "memory");                        \
  } while(0)

// Three GCN layers fused, one block per (sample, 7-row slab). (unchanged)
__global__ __launch_bounds__(256, 2)
void gcn_fused(const float* __restrict__ nodes,
               const float* __restrict__ W1, const float* __restrict__ b1,
               const float* __restrict__ W2, const float* __restrict__ b2,
               const float* __restrict__ W3, const float* __restrict__ b3,
               bf16* __restrict__ h3){
  __shared__ __align__(16) char smem[73216];
  float* regA = (float*)smem;
  float* regB = (float*)(smem + 36288);
  float* wbuf = (float*)(smem + 64512);
  float* W1s = wbuf;          float* b1s = wbuf + 32;
  float* W2s = wbuf + 48;     float* b2s = wbuf + 560;
  float* W3s = wbuf + 592;    float* b3s = wbuf + 2128;

  int tid = threadIdx.x;
  if (tid < 32)  W1s[tid] = W1[tid];
  if (tid < 16)  b1s[tid] = b1[tid];
  for (int t = tid; t < 512;  t += 256) W2s[t] = W2[t];
  if (tid < 32)  b2s[tid] = b2[tid];
  for (int t = tid; t < 1536; t += 256) W3s[t] = W3[t];
  if (tid < 48)  b3s[tid] = b3[tid];

  int b = blockIdx.x >> 2, s = blockIdx.x & 3;
  int base3 = s*7;
  int base2 = base3 - 1;
  int base1 = base3 - 2;
  const float* nb = nodes + (size_t)b*NN*2;
  __syncthreads();

  {
    float* h1s = regA;
    for (int t = tid; t < 308; t += 256){
      int lr = t/28, j = t - lr*28;
      int r = base1 + lr;
      float o[16] __attribute__((aligned(16)));
      if (r < 0 || r >= HG){
        #pragma unroll
        for (int f=0; f<16; f++) o[f] = 0.f;
      } else {
        float dn = dinv_ij(r,j);
        float a0 = dn*nb[(r*HG+j)*2+0], a1 = dn*nb[(r*HG+j)*2+1];
        if (r > 0)   { float w=dinv_ij(r-1,j); a0 += w*nb[((r-1)*HG+j)*2]; a1 += w*nb[((r-1)*HG+j)*2+1]; }
        if (r < HG-1){ float w=dinv_ij(r+1,j); a0 += w*nb[((r+1)*HG+j)*2]; a1 += w*nb[((r+1)*HG+j)*2+1]; }
        if (j > 0)   { float w=dinv_ij(r,j-1); a0 += w*nb[(r*HG+j-1)*2];   a1 += w*nb[(r*HG+j-1)*2+1]; }
        if (j < HG-1){ float w=dinv_ij(r,j+1); a0 += w*nb[(r*HG+j+1)*2];   a1 += w*nb[(r*HG+j+1)*2+1]; }
        a0 *= dn; a1 *= dn;
        #pragma unroll
        for (int f=0; f<16; f++) o[f] = fmaxf(a0*W1s[f] + a1*W1s[16+f] + b1s[f], 0.f);
      }
      float* dst = h1s + t*20;
      #pragma unroll
      for (int qq=0; qq<4; qq++) *(float4*)(dst + 4*qq) = *(float4*)&o[4*qq];
    }
  }
  __syncthreads();

  if (tid < 252){
    const float* h1s = regA;
    float* agg1 = regB;
    int lr = tid/28, j = tid - lr*28;
    int r = base2 + lr;
    float o[16] __attribute__((aligned(16)));
    if (r < 0 || r >= HG){
      #pragma unroll
      for (int f=0; f<16; f++) o[f] = 0.f;
    } else {
      int ln = (lr+1)*28 + j;
      float dn = dinv_ij(r,j);
      float wu = dinv_ij(r-1,j), wd = dinv_ij(r+1,j);
      float wl = (j>0)    ? dinv_ij(r,j-1) : 0.f;
      float wr = (j<HG-1) ? dinv_ij(r,j+1) : 0.f;
      const float* pc = h1s + ln*20;
      #pragma unroll
      for (int qq=0; qq<4; qq++){
        float4 vc = *(const float4*)(pc + 4*qq);
        float4 vu = *(const float4*)(pc - 28*20 + 4*qq);
        float4 vd = *(const float4*)(pc + 28*20 + 4*qq);
        float4 vl = *(const float4*)(pc - 20 + 4*qq);
        float4 vr = *(const float4*)(pc + 20 + 4*qq);
        o[4*qq+0] = dn*(dn*vc.x + wu*vu.x + wd*vd.x + wl*vl.x + wr*vr.x);
        o[4*qq+1] = dn*(dn*vc.y + wu*vu.y + wd*vd.y + wl*vl.y + wr*vr.y);
        o[4*qq+2] = dn*(dn*vc.z + wu*vu.z + wd*vd.z + wl*vl.z + wr*vr.z);
        o[4*qq+3] = dn*(dn*vc.w + wu*vu.w + wd*vd.w + wl*vl.w + wr*vr.w);
      }
    }
    float* dst = agg1 + tid*20;
    #pragma unroll
    for (int qq=0; qq<4; qq++) *(float4*)(dst + 4*qq) = *(float4*)&o[4*qq];
  }
  __syncthreads();

  {
    const float* agg1 = regB;
    float* h2s = regA;
    int tx = tid & 7, ty = tid >> 3;
    float4 w2r[16];
    #pragma unroll
    for (int fi=0; fi<16; fi++) w2r[fi] = *(const float4*)&W2s[fi*32 + tx*4];
    float4 bb = *(const float4*)&b2s[tx*4];
    #pragma unroll
    for (int i=0; i<8; i++){
      int n = ty + 32*i;
      if (n < 252){
        float af[16] __attribute__((aligned(16)));
        const float* ap = agg1 + n*20;
        #pragma unroll
        for (int qq=0; qq<4; qq++) *(float4*)&af[4*qq] = *(const float4*)(ap + 4*qq);
        float4 acc = bb;
        #pragma unroll
        for (int fi=0; fi<16; fi++){
          float a = af[fi];
          acc.x += a*w2r[fi].x; acc.y += a*w2r[fi].y;
          acc.z += a*w2r[fi].z; acc.w += a*w2r[fi].w;
        }
        acc.x = fmaxf(acc.x,0.f); acc.y = fmaxf(acc.y,0.f);
        acc.z = fmaxf(acc.z,0.f); acc.w = fmaxf(acc.w,0.f);
        *(float4*)&h2s[n*36 + tx*4] = acc;
      }
    }
  }
  __syncthreads();

  if (tid < 196){
    const float* h2s = regA;
    float* agg2 = regB;
    int lr = tid/28, j = tid - lr*28;
    int r = base3 + lr;
    int ln = (lr+1)*28 + j;
    float dn = dinv_ij(r,j);
    float wu = dinv_ij(r-1,j), wd = dinv_ij(r+1,j);
    float wl = (j>0)    ? dinv_ij(r,j-1) : 0.f;
    float wr = (j<HG-1) ? dinv_ij(r,j+1) : 0.f;
    const float* pc = h2s + ln*36;
    float* dst = agg2 + tid*36;
    #pragma unroll
    for (int qq=0; qq<8; qq++){
      float4 vc = *(const float4*)(pc + 4*qq);
      float4 vu = *(const float4*)(pc - 28*36 + 4*qq);
      float4 vd = *(const float4*)(pc + 28*36 + 4*qq);
      float4 vl = *(const float4*)(pc - 36 + 4*qq);
      float4 vr = *(const float4*)(pc + 36 + 4*qq);
      float4 o;
      o.x = dn*(dn*vc.x + wu*vu.x + wd*vd.x + wl*vl.x + wr*vr.x);
      o.y = dn*(dn*vc.y + wu*vu.y + wd*vd.y + wl*vl.y + wr*vr.y);
      o.z = dn*(dn*vc.z + wu*vu.z + wd*vd.z + wl*vl.z + wr*vr.z);
      o.w = dn*(dn*vc.w + wu*vu.w + wd*vd.w + wl*vl.w + wr*vr.w);
      *(float4*)(dst + 4*qq) = o;
    }
  }
  __syncthreads();

  {
    bf16* h3buf = (bf16*)regA;
    if (tid < 252){
      const float* agg2 = regB;
      int tx = tid % 12, ty = tid / 12;
      float4 w3r[32];
      #pragma unroll
      for (int fi=0; fi<32; fi++) w3r[fi] = *(const float4*)&W3s[fi*48 + tx*4];
      float4 bb = *(const float4*)&b3s[tx*4];
      #pragma unroll
      for (int i=0; i<10; i++){
        int n = ty + 21*i;
        if (n < 196){
          float af[32] __attribute__((aligned(16)));
          const float* ap = agg2 + n*36;
          #pragma unroll
          for (int qq=0; qq<8; qq++) *(float4*)&af[4*qq] = *(const float4*)(ap + 4*qq);
          float4 acc = bb;
          #pragma unroll
          for (int fi=0; fi<32; fi++){
            float a = af[fi];
            acc.x += a*w3r[fi].x; acc.y += a*w3r[fi].y;
            acc.z += a*w3r[fi].z; acc.w += a*w3r[fi].w;
          }
          uint2 pv;
          pv.x = pk2(fmaxf(acc.x,0.f), fmaxf(acc.y,0.f));
          pv.y = pk2(fmaxf(acc.z,0.f), fmaxf(acc.w,0.f));
          *(uint2*)((char*)h3buf + n*112 + tx*8) = pv;
        }
      }
    }
  }
  __syncthreads();

  {
    const char* h3buf = (const char*)regA;
    uint4* dst = (uint4*)(h3 + ((size_t)b*NN + base3*28)*F3);
    for (int t = tid; t < 1176; t += 256){
      int n = t/6, gq = t - n*6;
      dst[t] = *(const uint4*)(h3buf + n*112 + gq*16);
    }
  }
}

// Gumbel-softmax + einsum via MFMA (r15-exact register-light version, 193us).
__global__
void einsum_mfma_kernel(const float* __restrict__ logits, const float* __restrict__ gumbel,
                        const bf16* __restrict__ h3, float* __restrict__ g){
  __shared__ __align__(16) unsigned smemS[7488];   // dh[80][36] | dl[80][36] | ht[48][36]
  const int SLO = 2880, HTO = 5760;

  int b = blockIdx.x, tid = threadIdx.x;
  int l = tid & 63, w = tid >> 6;
  int n_loc = tid >> 2, q = tid & 3;
  int kstart = q << 4;
  int kcnt = (q < 3) ? 16 : 22;
  int kc2 = kcnt >> 1;
  int m_pair = tid >> 3;
  int half = (tid >> 2) & 1;
  int ks = w >> 1, mh = w & 1;
  int mtoff = mh ? 3 : 0, mtcnt = mh ? 2 : 3;

  for (int t = tid; t < 720; t += 256){
    int bb2 = t >= 360, r = t - bb2*360;
    if (bb2) smemS[SLO + 2520 + r] = 0u;
    else     smemS[2520 + r] = 0u;
  }

  f32x4 acc[3][3];
  #pragma unroll
  for (int mt=0; mt<3; mt++)
    #pragma unroll
    for (int bt=0; bt<3; bt++) acc[mt][bt] = (f32x4){0.f,0.f,0.f,0.f};

  int hm0 = tid/12, hj0 = tid - hm0*12;
  int tt1 = tid + 256;
  int hm1 = tt1/12, hj1 = tt1 - hm1*12;

  auto consume_pack = [&](int c){
    int c0 = c << 6;
    int node = c0 + n_loc;
    bool v = node < NN;
    const float* lp = logits + ((size_t)b*NN + node)*KK + kstart;
    const float* gp = gumbel + ((size_t)b*NN + node)*KK + kstart;
    int nld = (q < 3) ? 8 : 11;
    float x[22];
    #pragma unroll
    for (int s=0; s<11; s++){
      bool a = v && (s < nld);
      float2 lv = a ? *(const float2*)(lp + 2*s) : (float2){0.f,0.f};
      float2 gv = a ? *(const float2*)(gp + 2*s) : (float2){0.f,0.f};
      x[2*s]   = 2.f*(lv.x + gv.x);
      x[2*s+1] = 2.f*(lv.y + gv.y);
    }
    float mx = -1e30f;
    #pragma unroll
    for (int i=0; i<22; i++) if (i < kcnt) mx = fmaxf(mx, x[i]);
    mx = fmaxf(mx, __shfl_xor(mx, 1));
    mx = fmaxf(mx, __shfl_xor(mx, 2));
    float sum = 0.f;
    #pragma unroll
    for (int i=0; i<22; i++) if (i < kcnt){ x[i] = __expf(x[i]-mx); sum += x[i]; }
    sum += __shfl_xor(sum, 1);
    sum += __shfl_xor(sum, 2);
    float rs = v ? 1.0f/sum : 0.f;
    #pragma unroll
    for (int i=0; i<22; i++){
      if (i < kcnt){
        float p = x[i]*rs;
        unsigned hb = (unsigned)(unsigned short)bfbits(p);
        union { short s; bf16 h; } uh; uh.s = (short)hb;
        float lo = p - __bfloat162float(uh.h);
        unsigned lb = (unsigned)(unsigned short)bfbits(lo);
        unsigned phb = (unsigned)__shfl_xor((int)hb, 4);
        unsigned plb = (unsigned)__shfl_xor((int)lb, 4);
        unsigned dh = (half==0) ? (hb | (phb<<16)) : (phb | (hb<<16));
        unsigned dl = (half==0) ? (lb | (plb<<16)) : (plb | (lb<<16));
        bool doW = (half==0) ? (i < kc2) : (i >= kc2);
        if (doW){
          int k = kstart + i;
          int col = m_pair ^ (((k>>4)&3)<<3);
          smemS[k*36 + col] = dh;
          smemS[SLO + k*36 + col] = dl;
        }
      }
    }
    {
      bool vA0 = (c0 + 2*hm0)     < NN;
      bool vB0 = (c0 + 2*hm0 + 1) < NN;
      const uint2* p0 = (const uint2*)(h3 + ((size_t)b*NN + c0 + 2*hm0)*F3 + 4*hj0);
      uint2 hA0 = vA0 ? p0[0]  : (uint2){0u,0u};
      uint2 hB0 = vB0 ? p0[12] : (uint2){0u,0u};
      unsigned d0 = (hA0.x & 0xFFFFu) | (hB0.x << 16);
      unsigned d1 = (hA0.x >> 16)     | (hB0.x & 0xFFFF0000u);
      unsigned d2 = (hA0.y & 0xFFFFu) | (hB0.y << 16);
      unsigned d3 = (hA0.y >> 16)     | (hB0.y & 0xFFFF0000u);
      #pragma unroll
      for (int i2=0; i2<4; i2++){
        int f = 4*hj0 + i2;
        int col = hm0 ^ (((f>>4)&3)<<3);
        unsigned dv = (i2==0)?d0:(i2==1)?d1:(i2==2)?d2:d3;
        smemS[HTO + f*36 + col] = dv;
      }
      if (tid < 128){
        bool vA1 = (c0 + 2*hm1)     < NN;
        bool vB1 = (c0 + 2*hm1 + 1) < NN;
        const uint2* p1 = (const uint2*)(h3 + ((size_t)b*NN + c0 + 2*hm1)*F3 + 4*hj1);
        uint2 hA1 = vA1 ? p1[0]  : (uint2){0u,0u};
        uint2 hB1 = vB1 ? p1[12] : (uint2){0u,0u};
        unsigned e0 = (hA1.x & 0xFFFFu) | (hB1.x << 16);
        unsigned e1 = (hA1.x >> 16)     | (hB1.x & 0xFFFF0000u);
        unsigned e2 = (hA1.y & 0xFFFFu) | (hB1.y << 16);
        unsigned e3 = (hA1.y >> 16)     | (hB1.y & 0xFFFF0000u);
        #pragma unroll
        for (int i2=0; i2<4; i2++){
          int f = 4*hj1 + i2;
          int col = hm1 ^ (((f>>4)&3)<<3);
          unsigned dv = (i2==0)?e0:(i2==1)?e1:(i2==2)?e2:e3;
          smemS[HTO + f*36 + col] = dv;
        }
      }
    }
  };

  auto mfma_phase = [&](){
    int pr = (ks<<4) + ((l>>4)<<2);
    s8v Af[3], Al[3], Bf[3];
    #pragma unroll
    for (int mt=0; mt<3; mt++) if (mt < mtcnt){
      int row = (mtoff+mt)*16 + (l&15);
      int col = pr ^ (((row>>4)&3)<<3);
      Af[mt] = *(const s8v*)&smemS[row*36 + col];
      Al[mt] = *(const s8v*)&smemS[SLO + row*36 + col];
    }
    #pragma unroll
    for (int bt=0; bt<3; bt++){
      int f = bt*16 + (l&15);
      int col = pr ^ (((f>>4)&3)<<3);
      Bf[bt] = *(const s8v*)&smemS[HTO + f*36 + col];
    }
    #pragma unroll
    for (int mt=0; mt<3; mt++) if (mt < mtcnt)
      #pragma unroll
      for (int bt=0; bt<3; bt++){
        acc[mt][bt] = __builtin_amdgcn_mfma_f32_16x16x32_bf16(Af[mt], Bf[bt], acc[mt][bt], 0, 0, 0);
        acc[mt][bt] = __builtin_amdgcn_mfma_f32_16x16x32_bf16(Al[mt], Bf[bt], acc[mt][bt], 0, 0, 0);
      }
  };

  consume_pack(0);
  SYNC_LDS();

  for (int c = 0; c < 13; c++){
    mfma_phase();
    if (c < 12){
      SYNC_LDS();
      consume_pack(c+1);
      SYNC_LDS();
    }
  }

  __syncthreads();
  float* cred = (float*)&smemS[0];
  if (ks == 0){
    #pragma unroll
    for (int mt=0; mt<3; mt++) if (mt < mtcnt)
      #pragma unroll
      for (int bt=0; bt<3; bt++)
        #pragma unroll
        for (int r=0; r<4; r++){
          int row = (mtoff+mt)*16 + (l>>4)*4 + r;
          int col = bt*16 + (l&15);
          cred[row*49 + col] = acc[mt][bt][r];
        }
  }
  __syncthreads();
  if (ks == 1){
    #pragma unroll
    for (int mt=0; mt<3; mt++) if (mt < mtcnt)
      #pragma unroll
      for (int bt=0; bt<3; bt++)
        #pragma unroll
        for (int r=0; r<4; r++){
          int row = (mtoff+mt)*16 + (l>>4)*4 + r;
          int col = bt*16 + (l&15);
          cred[row*49 + col] += acc[mt][bt][r];
        }
  }
  __syncthreads();
  for (int t = tid; t < KK*F3; t += 256){
    int r = t / F3, c2 = t - r*F3;
    g[(size_t)b*(KK*F3) + t] = cred[r*49 + c2];
  }
}

// Register-prefetch dense: out = act(A @ W + b). ACT: 0=relu,1=sigmoid,2=partial.
template<int ACT>
__global__ __launch_bounds__(256)
void dense_kernel(const float* __restrict__ A, const float* __restrict__ W,
                  const float* __restrict__ bias, float* __restrict__ out,
                  int M, int K, int Nn, int kChunk){
  __shared__ float As[16][65];
  __shared__ float Bs[16][64];
  int tx = threadIdx.x & 15, ty = threadIdx.x >> 4;
  int m0 = blockIdx.x*64, n0 = blockIdx.y*64;
  int ks = blockIdx.z * kChunk;
  int ke = min(K, ks + kChunk);
  int a_kk = threadIdx.x & 15, a_mm = threadIdx.x >> 4;
  int b_nn = threadIdx.x & 63, b_k0 = threadIdx.x >> 6;
  float ra[4], rb[4];
  float acc[4][4] = {};

  #pragma unroll
  for (int s=0; s<4; s++){
    int gk = ks + a_kk;
    ra[s] = (gk < ke) ? A[(size_t)(m0 + a_mm + s*16)*K + gk] : 0.f;
  }
  #pragma unroll
  for (int s=0; s<4; s++){
    int gk = ks + b_k0 + s*4, gn = n0 + b_nn;
    rb[s] = (gk < ke && gn < Nn) ? W[(size_t)gk*Nn + gn] : 0.f;
  }

  for (int k0 = ks; k0 < ke; k0 += 16){
    #pragma unroll
    for (int s=0; s<4; s++) As[a_kk][a_mm + s*16] = ra[s];
    #pragma unroll
    for (int s=0; s<4; s++) Bs[b_k0 + s*4][b_nn] = rb[s];
    __syncthreads();
    if (k0 + 16 < ke){
      #pragma unroll
      for (int s=0; s<4; s++){
        int gk = k0 + 16 + a_kk;
        ra[s] = (gk < ke) ? A[(size_t)(m0 + a_mm + s*16)*K + gk] : 0.f;
      }
      #pragma unroll
      for (int s=0; s<4; s++){
        int gk = k0 + 16 + b_k0 + s*4, gn = n0 + b_nn;
        rb[s] = (gk < ke && gn < Nn) ? W[(size_t)gk*Nn + gn] : 0.f;
      }
    }
    #pragma unroll
    for (int kk=0; kk<16; kk++){
      float a[4], bv[4];
      #pragma unroll
      for (int i2=0; i2<4; i2++) a[i2] = As[kk][ty*4+i2];
      #pragma unroll
      for (int j2=0; j2<4; j2++) bv[j2] = Bs[kk][tx*4+j2];
      #pragma unroll
      for (int i2=0; i2<4; i2++)
        #pragma unroll
        for (int j2=0; j2<4; j2++) acc[i2][j2] += a[i2]*bv[j2];
    }
    __syncthreads();
  }

  if (ACT == 2){
    float* po = out + (size_t)blockIdx.z*M*Nn;
    #pragma unroll
    for (int j2=0; j2<4; j2++){
      int gn = n0 + tx*4 + j2;
      if (gn < Nn){
        #pragma unroll
        for (int i2=0; i2<4; i2++)
          po[(size_t)(m0 + ty*4 + i2)*Nn + gn] = acc[i2][j2];
      }
    }
  } else {
    #pragma unroll
    for (int j2=0; j2<4; j2++){
      int gn = n0 + tx*4 + j2;
      if (gn < Nn){
        float bb = bias[gn];
        #pragma unroll
        for (int i2=0; i2<4; i2++){
          float v = acc[i2][j2] + bb;
          v = (ACT == 0) ? fmaxf(v, 0.f) : 1.0f/(1.0f + __expf(-v));
          out[(size_t)(m0 + ty*4 + i2)*Nn + gn] = v;
        }
      }
    }
  }
}

// split-K partial reduction + bias + activation (0=relu, 1=sigmoid)
template<int ACT>
__global__ __launch_bounds__(256)
void reduce_bias_act(const float* __restrict__ part, const float* __restrict__ bias,
                     float* __restrict__ out, int M, int Nn, int S){
  int idx = blockIdx.x*256 + threadIdx.x;
  if (idx >= M*Nn) return;
  int n = idx % Nn;
  float s = bias[n];
  for (int i=0; i<S; i++) s += part[(size_t)i*M*Nn + idx];
  out[idx] = (ACT == 0) ? fmaxf(s, 0.f) : 1.0f/(1.0f + __expf(-s));
}

// Fused mid-tail: e2 = relu(e1@We2+b); mu/var heads; reparam; dd = relu(z@Wd1+b).
// One block per 4 batch rows (256 blocks). All f32; weights stream via L2.
__global__ __launch_bounds__(256)
void encoder_tail(const float* __restrict__ e1,
                  const float* __restrict__ We2, const float* __restrict__ be2,
                  const float* __restrict__ Wmu, const float* __restrict__ bmu,
                  const float* __restrict__ Wvr, const float* __restrict__ bvr,
                  const float* __restrict__ Wd1, const float* __restrict__ bd1,
                  const float* __restrict__ eps, float* __restrict__ dd){
  __shared__ float e1s[4][400];
  __shared__ float e2s[4][400];
  __shared__ float zs[4][72];
  int tid = threadIdx.x;
  int r0 = blockIdx.x * 4;
  int col = tid & 63, row = tid >> 6;    // 64 cols x 4 rows

  // load e1 rows (coalesced)
  for (int t = tid; t < 1600; t += 256)
    e1s[t/400][t - (t/400)*400] = e1[(size_t)(r0 + t/400)*HD + (t - (t/400)*400)];
  __syncthreads();

  // phase 2: e2[row][n] for n = col + 64*t
  for (int n0 = 0; n0 < 400; n0 += 64){
    int n = n0 + col;
    if (n < 400){
      float a = be2[n];
      const float* er = e1s[row];
      for (int k = 0; k < 400; k++) a += er[k] * We2[(size_t)k*HD + n];
      e2s[row][n] = fmaxf(a, 0.f);
    }
  }
  __syncthreads();

  // phase 3: mu/var + reparameterize -> zs[row][zi], zi = col (+64)
  for (int zi = col; zi < ZD; zi += 64){
    float amu = bmu[zi], avr = bvr[zi];
    const float* er = e2s[row];
    for (int k = 0; k < 400; k++){
      float e = er[k];
      amu += e * Wmu[(size_t)k*ZD + zi];
      avr += e * Wvr[(size_t)k*ZD + zi];
    }
    float sp = fmaxf(avr, 0.f) + log1pf(__expf(-fabsf(avr)));
    zs[row][zi] = amu + eps[(size_t)(r0 + row)*ZD + zi] * sqrtf(sp + 1e-10f);
  }
  __syncthreads();

  // phase 4: dd[row][n] = relu(z @ Wd1 + b)
  for (int n0 = 0; n0 < 400; n0 += 64){
    int n = n0 + col;
    if (n < 400){
      float a = bd1[n];
      const float* zr = zs[row];
      for (int k = 0; k < ZD; k++) a += zr[k] * Wd1[(size_t)k*HD + n];
      dd[(size_t)(r0 + row)*HD + n] = fmaxf(a, 0.f);
    }
  }
}

extern "C" void kernel_launch(void* const* d_in, const int* in_sizes, int n_in,
                              void* d_out, int out_size, void* d_ws, size_t ws_size,
                              hipStream_t stream){
  (void)in_sizes; (void)n_in; (void)out_size; (void)ws_size;
  const float* nodes  = (const float*)d_in[0];
  const float* logits = (const float*)d_in[1];
  const float* gumbel = (const float*)d_in[2];
  const float* eps    = (const float*)d_in[3];
  const float* W1 =(const float*)d_in[4],  *b1 =(const float*)d_in[5];
  const float* W2 =(const float*)d_in[6],  *b2 =(const float*)d_in[7];
  const float* W3 =(const float*)d_in[8],  *b3 =(const float*)d_in[9];
  const float* We1=(const float*)d_in[10], *be1=(const float*)d_in[11];
  const float* We2=(const float*)d_in[12], *be2=(const float*)d_in[13];
  const float* Wmu=(const float*)d_in[14], *bmu=(const float*)d_in[15];
  const float* Wvr=(const float*)d_in[16], *bvr=(const float*)d_in[17];
  const float* Wd1=(const float*)d_in[18], *bd1=(const float*)d_in[19];
  const float* Wd2=(const float*)d_in[20], *bd2=(const float*)d_in[21];

  char* ws = (char*)d_ws;
  bf16*  h3 = (bf16*)(ws);                 // 77,070,336 B
  float* g  = (float*)(ws + 77070336);     // 13,762,560 B
  float* e1 = (float*)(ws + 90832896);
  float* dd = (float*)(ws + 94396416);
  float* part = (float*)(ws);              // aliases h3 (dead after einsum)
  float* out = (float*)d_out;

  gcn_fused<<<4096, 256, 0, stream>>>(nodes, W1, b1, W2, b2, W3, b3, h3);
  einsum_mfma_kernel<<<1024, 256, 0, stream>>>(logits, gumbel, h3, g);
  dense_kernel<2><<<dim3(16, 7, 8), 256, 0, stream>>>(g, We1, nullptr, part, 1024, 3360, 400, 432);
  reduce_bias_act<0><<<1600, 256, 0, stream>>>(part, be1, e1, 1024, 400, 8);
  encoder_tail<<<256, 256, 0, stream>>>(e1, We2, be2, Wmu, bmu, Wvr, bvr, Wd1, bd1, eps, dd);
  dense_kernel<2><<<dim3(16, 13, 4), 256, 0, stream>>>(dd, Wd2, nullptr, part, 1024, 400, 784, 112);
  reduce_bias_act<1><<<3136, 256, 0, stream>>>(part, bd2, out, 1024, 784, 4);
}

// Round 18
// 400.297 us; speedup vs baseline: 1.9163x; 1.2331x over previous
//
#include <hip/hip_runtime.h>
#include <hip/hip_bf16.h>

// VAE with grid-GCN encoder, MI355X. Round 17: exact revert to the r15
// configuration (best measured: 401.6us) after the encoder_tail fusion
// regressed (+92us, serial-chain latency-bound). gcn r6-form + register-light
// einsum + split-K dense chain.

#define BB 1024
#define HG 28
#define NN 784
#define KK 70
#define F3 48
#define HD 400
#define ZD 70
#define IMGD 784

typedef __hip_bfloat16 bf16;
typedef __attribute__((ext_vector_type(8))) short s8v;
typedef __attribute__((ext_vector_type(4))) float f32x4;

__device__ __forceinline__ float dinv_ij(int i, int j){
  int deg = 1 + (i>0) + (i<HG-1) + (j>0) + (j<HG-1);
  return rsqrtf((float)deg);
}

__device__ __forceinline__ unsigned pk2(float a, float b){
  union { bf16 h; unsigned short u; } ua, ub;
  ua.h = __float2bfloat16(a); ub.h = __float2bfloat16(b);
  return ((unsigned)ub.u << 16) | ua.u;
}

__device__ __forceinline__ short bfbits(float v){
  union { bf16 h; short s; } u; u.h = __float2bfloat16(v); return u.s;
}

// LDS-visibility barrier WITHOUT vmcnt drain.
#define SYNC_LDS() do {                                   \
    asm volatile("" ::: "memory");                        \
    asm volatile("s_waitcnt lgkmcnt(0)" ::: "memory");    \
    __builtin_amdgcn_s_barrier();                         \
    asm volatile("" ::: "memory");                        \
  } while(0)

// Three GCN layers fused, one block per (sample, 7-row slab).
__global__ __launch_bounds__(256, 2)
void gcn_fused(const float* __restrict__ nodes,
               const float* __restrict__ W1, const float* __restrict__ b1,
               const float* __restrict__ W2, const float* __restrict__ b2,
               const float* __restrict__ W3, const float* __restrict__ b3,
               bf16* __restrict__ h3){
  __shared__ __align__(16) char smem[73216];
  float* regA = (float*)smem;
  float* regB = (float*)(smem + 36288);
  float* wbuf = (float*)(smem + 64512);
  float* W1s = wbuf;          float* b1s = wbuf + 32;
  float* W2s = wbuf + 48;     float* b2s = wbuf + 560;
  float* W3s = wbuf + 592;    float* b3s = wbuf + 2128;

  int tid = threadIdx.x;
  if (tid < 32)  W1s[tid] = W1[tid];
  if (tid < 16)  b1s[tid] = b1[tid];
  for (int t = tid; t < 512;  t += 256) W2s[t] = W2[t];
  if (tid < 32)  b2s[tid] = b2[tid];
  for (int t = tid; t < 1536; t += 256) W3s[t] = W3[t];
  if (tid < 48)  b3s[tid] = b3[tid];

  int b = blockIdx.x >> 2, s = blockIdx.x & 3;
  int base3 = s*7;
  int base2 = base3 - 1;
  int base1 = base3 - 2;
  const float* nb = nodes + (size_t)b*NN*2;
  __syncthreads();

  // P1: layer 1 -> h1s[308][20]
  {
    float* h1s = regA;
    for (int t = tid; t < 308; t += 256){
      int lr = t/28, j = t - lr*28;
      int r = base1 + lr;
      float o[16] __attribute__((aligned(16)));
      if (r < 0 || r >= HG){
        #pragma unroll
        for (int f=0; f<16; f++) o[f] = 0.f;
      } else {
        float dn = dinv_ij(r,j);
        float a0 = dn*nb[(r*HG+j)*2+0], a1 = dn*nb[(r*HG+j)*2+1];
        if (r > 0)   { float w=dinv_ij(r-1,j); a0 += w*nb[((r-1)*HG+j)*2]; a1 += w*nb[((r-1)*HG+j)*2+1]; }
        if (r < HG-1){ float w=dinv_ij(r+1,j); a0 += w*nb[((r+1)*HG+j)*2]; a1 += w*nb[((r+1)*HG+j)*2+1]; }
        if (j > 0)   { float w=dinv_ij(r,j-1); a0 += w*nb[(r*HG+j-1)*2];   a1 += w*nb[(r*HG+j-1)*2+1]; }
        if (j < HG-1){ float w=dinv_ij(r,j+1); a0 += w*nb[(r*HG+j+1)*2];   a1 += w*nb[(r*HG+j+1)*2+1]; }
        a0 *= dn; a1 *= dn;
        #pragma unroll
        for (int f=0; f<16; f++) o[f] = fmaxf(a0*W1s[f] + a1*W1s[16+f] + b1s[f], 0.f);
      }
      float* dst = h1s + t*20;
      #pragma unroll
      for (int qq=0; qq<4; qq++) *(float4*)(dst + 4*qq) = *(float4*)&o[4*qq];
    }
  }
  __syncthreads();

  // P2: agg1[252][20]
  if (tid < 252){
    const float* h1s = regA;
    float* agg1 = regB;
    int lr = tid/28, j = tid - lr*28;
    int r = base2 + lr;
    float o[16] __attribute__((aligned(16)));
    if (r < 0 || r >= HG){
      #pragma unroll
      for (int f=0; f<16; f++) o[f] = 0.f;
    } else {
      int ln = (lr+1)*28 + j;
      float dn = dinv_ij(r,j);
      float wu = dinv_ij(r-1,j), wd = dinv_ij(r+1,j);
      float wl = (j>0)    ? dinv_ij(r,j-1) : 0.f;
      float wr = (j<HG-1) ? dinv_ij(r,j+1) : 0.f;
      const float* pc = h1s + ln*20;
      #pragma unroll
      for (int qq=0; qq<4; qq++){
        float4 vc = *(const float4*)(pc + 4*qq);
        float4 vu = *(const float4*)(pc - 28*20 + 4*qq);
        float4 vd = *(const float4*)(pc + 28*20 + 4*qq);
        float4 vl = *(const float4*)(pc - 20 + 4*qq);
        float4 vr = *(const float4*)(pc + 20 + 4*qq);
        o[4*qq+0] = dn*(dn*vc.x + wu*vu.x + wd*vd.x + wl*vl.x + wr*vr.x);
        o[4*qq+1] = dn*(dn*vc.y + wu*vu.y + wd*vd.y + wl*vl.y + wr*vr.y);
        o[4*qq+2] = dn*(dn*vc.z + wu*vu.z + wd*vd.z + wl*vl.z + wr*vr.z);
        o[4*qq+3] = dn*(dn*vc.w + wu*vu.w + wd*vd.w + wl*vl.w + wr*vr.w);
      }
    }
    float* dst = agg1 + tid*20;
    #pragma unroll
    for (int qq=0; qq<4; qq++) *(float4*)(dst + 4*qq) = *(float4*)&o[4*qq];
  }
  __syncthreads();

  // P3: L2-GEMM h2s[252][36]
  {
    const float* agg1 = regB;
    float* h2s = regA;
    int tx = tid & 7, ty = tid >> 3;
    float4 w2r[16];
    #pragma unroll
    for (int fi=0; fi<16; fi++) w2r[fi] = *(const float4*)&W2s[fi*32 + tx*4];
    float4 bb = *(const float4*)&b2s[tx*4];
    #pragma unroll
    for (int i=0; i<8; i++){
      int n = ty + 32*i;
      if (n < 252){
        float af[16] __attribute__((aligned(16)));
        const float* ap = agg1 + n*20;
        #pragma unroll
        for (int qq=0; qq<4; qq++) *(float4*)&af[4*qq] = *(const float4*)(ap + 4*qq);
        float4 acc = bb;
        #pragma unroll
        for (int fi=0; fi<16; fi++){
          float a = af[fi];
          acc.x += a*w2r[fi].x; acc.y += a*w2r[fi].y;
          acc.z += a*w2r[fi].z; acc.w += a*w2r[fi].w;
        }
        acc.x = fmaxf(acc.x,0.f); acc.y = fmaxf(acc.y,0.f);
        acc.z = fmaxf(acc.z,0.f); acc.w = fmaxf(acc.w,0.f);
        *(float4*)&h2s[n*36 + tx*4] = acc;
      }
    }
  }
  __syncthreads();

  // P4: agg2[196][36]
  if (tid < 196){
    const float* h2s = regA;
    float* agg2 = regB;
    int lr = tid/28, j = tid - lr*28;
    int r = base3 + lr;
    int ln = (lr+1)*28 + j;
    float dn = dinv_ij(r,j);
    float wu = dinv_ij(r-1,j), wd = dinv_ij(r+1,j);
    float wl = (j>0)    ? dinv_ij(r,j-1) : 0.f;
    float wr = (j<HG-1) ? dinv_ij(r,j+1) : 0.f;
    const float* pc = h2s + ln*36;
    float* dst = agg2 + tid*36;
    #pragma unroll
    for (int qq=0; qq<8; qq++){
      float4 vc = *(const float4*)(pc + 4*qq);
      float4 vu = *(const float4*)(pc - 28*36 + 4*qq);
      float4 vd = *(const float4*)(pc + 28*36 + 4*qq);
      float4 vl = *(const float4*)(pc - 36 + 4*qq);
      float4 vr = *(const float4*)(pc + 36 + 4*qq);
      float4 o;
      o.x = dn*(dn*vc.x + wu*vu.x + wd*vd.x + wl*vl.x + wr*vr.x);
      o.y = dn*(dn*vc.y + wu*vu.y + wd*vd.y + wl*vl.y + wr*vr.y);
      o.z = dn*(dn*vc.z + wu*vu.z + wd*vd.z + wl*vl.z + wr*vr.z);
      o.w = dn*(dn*vc.w + wu*vu.w + wd*vd.w + wl*vl.w + wr*vr.w);
      *(float4*)(dst + 4*qq) = o;
    }
  }
  __syncthreads();

  // P5: L3-GEMM h3buf[196][56]bf16 (r6 form, spill-free)
  {
    bf16* h3buf = (bf16*)regA;
    if (tid < 252){
      const float* agg2 = regB;
      int tx = tid % 12, ty = tid / 12;
      float4 w3r[32];
      #pragma unroll
      for (int fi=0; fi<32; fi++) w3r[fi] = *(const float4*)&W3s[fi*48 + tx*4];
      float4 bb = *(const float4*)&b3s[tx*4];
      #pragma unroll
      for (int i=0; i<10; i++){
        int n = ty + 21*i;
        if (n < 196){
          float af[32] __attribute__((aligned(16)));
          const float* ap = agg2 + n*36;
          #pragma unroll
          for (int qq=0; qq<8; qq++) *(float4*)&af[4*qq] = *(const float4*)(ap + 4*qq);
          float4 acc = bb;
          #pragma unroll
          for (int fi=0; fi<32; fi++){
            float a = af[fi];
            acc.x += a*w3r[fi].x; acc.y += a*w3r[fi].y;
            acc.z += a*w3r[fi].z; acc.w += a*w3r[fi].w;
          }
          uint2 pv;
          pv.x = pk2(fmaxf(acc.x,0.f), fmaxf(acc.y,0.f));
          pv.y = pk2(fmaxf(acc.z,0.f), fmaxf(acc.w,0.f));
          *(uint2*)((char*)h3buf + n*112 + tx*8) = pv;
        }
      }
    }
  }
  __syncthreads();

  // P6: coalesced copyout
  {
    const char* h3buf = (const char*)regA;
    uint4* dst = (uint4*)(h3 + ((size_t)b*NN + base3*28)*F3);
    for (int t = tid; t < 1176; t += 256){
      int n = t/6, gq = t - n*6;
      dst[t] = *(const uint4*)(h3buf + n*112 + gq*16);
    }
  }
}

// Gumbel-softmax + einsum via MFMA (register-light r15 version).
__global__
void einsum_mfma_kernel(const float* __restrict__ logits, const float* __restrict__ gumbel,
                        const bf16* __restrict__ h3, float* __restrict__ g){
  __shared__ __align__(16) unsigned smemS[7488];   // dh[80][36] | dl[80][36] | ht[48][36]
  const int SLO = 2880, HTO = 5760;

  int b = blockIdx.x, tid = threadIdx.x;
  int l = tid & 63, w = tid >> 6;
  int n_loc = tid >> 2, q = tid & 3;
  int kstart = q << 4;
  int kcnt = (q < 3) ? 16 : 22;
  int kc2 = kcnt >> 1;
  int m_pair = tid >> 3;
  int half = (tid >> 2) & 1;
  int ks = w >> 1, mh = w & 1;
  int mtoff = mh ? 3 : 0, mtcnt = mh ? 2 : 3;

  for (int t = tid; t < 720; t += 256){
    int bb2 = t >= 360, r = t - bb2*360;
    if (bb2) smemS[SLO + 2520 + r] = 0u;
    else     smemS[2520 + r] = 0u;
  }

  f32x4 acc[3][3];
  #pragma unroll
  for (int mt=0; mt<3; mt++)
    #pragma unroll
    for (int bt=0; bt<3; bt++) acc[mt][bt] = (f32x4){0.f,0.f,0.f,0.f};

  int hm0 = tid/12, hj0 = tid - hm0*12;
  int tt1 = tid + 256;
  int hm1 = tt1/12, hj1 = tt1 - hm1*12;

  auto consume_pack = [&](int c){
    int c0 = c << 6;
    int node = c0 + n_loc;
    bool v = node < NN;
    const float* lp = logits + ((size_t)b*NN + node)*KK + kstart;
    const float* gp = gumbel + ((size_t)b*NN + node)*KK + kstart;
    int nld = (q < 3) ? 8 : 11;
    float x[22];
    #pragma unroll
    for (int s=0; s<11; s++){
      bool a = v && (s < nld);
      float2 lv = a ? *(const float2*)(lp + 2*s) : (float2){0.f,0.f};
      float2 gv = a ? *(const float2*)(gp + 2*s) : (float2){0.f,0.f};
      x[2*s]   = 2.f*(lv.x + gv.x);
      x[2*s+1] = 2.f*(lv.y + gv.y);
    }
    float mx = -1e30f;
    #pragma unroll
    for (int i=0; i<22; i++) if (i < kcnt) mx = fmaxf(mx, x[i]);
    mx = fmaxf(mx, __shfl_xor(mx, 1));
    mx = fmaxf(mx, __shfl_xor(mx, 2));
    float sum = 0.f;
    #pragma unroll
    for (int i=0; i<22; i++) if (i < kcnt){ x[i] = __expf(x[i]-mx); sum += x[i]; }
    sum += __shfl_xor(sum, 1);
    sum += __shfl_xor(sum, 2);
    float rs = v ? 1.0f/sum : 0.f;
    #pragma unroll
    for (int i=0; i<22; i++){
      if (i < kcnt){
        float p = x[i]*rs;
        unsigned hb = (unsigned)(unsigned short)bfbits(p);
        union { short s; bf16 h; } uh; uh.s = (short)hb;
        float lo = p - __bfloat162float(uh.h);
        unsigned lb = (unsigned)(unsigned short)bfbits(lo);
        unsigned phb = (unsigned)__shfl_xor((int)hb, 4);
        unsigned plb = (unsigned)__shfl_xor((int)lb, 4);
        unsigned dh = (half==0) ? (hb | (phb<<16)) : (phb | (hb<<16));
        unsigned dl = (half==0) ? (lb | (plb<<16)) : (plb | (lb<<16));
        bool doW = (half==0) ? (i < kc2) : (i >= kc2);
        if (doW){
          int k = kstart + i;
          int col = m_pair ^ (((k>>4)&3)<<3);
          smemS[k*36 + col] = dh;
          smemS[SLO + k*36 + col] = dl;
        }
      }
    }
    {
      bool vA0 = (c0 + 2*hm0)     < NN;
      bool vB0 = (c0 + 2*hm0 + 1) < NN;
      const uint2* p0 = (const uint2*)(h3 + ((size_t)b*NN + c0 + 2*hm0)*F3 + 4*hj0);
      uint2 hA0 = vA0 ? p0[0]  : (uint2){0u,0u};
      uint2 hB0 = vB0 ? p0[12] : (uint2){0u,0u};
      unsigned d0 = (hA0.x & 0xFFFFu) | (hB0.x << 16);
      unsigned d1 = (hA0.x >> 16)     | (hB0.x & 0xFFFF0000u);
      unsigned d2 = (hA0.y & 0xFFFFu) | (hB0.y << 16);
      unsigned d3 = (hA0.y >> 16)     | (hB0.y & 0xFFFF0000u);
      #pragma unroll
      for (int i2=0; i2<4; i2++){
        int f = 4*hj0 + i2;
        int col = hm0 ^ (((f>>4)&3)<<3);
        unsigned dv = (i2==0)?d0:(i2==1)?d1:(i2==2)?d2:d3;
        smemS[HTO + f*36 + col] = dv;
      }
      if (tid < 128){
        bool vA1 = (c0 + 2*hm1)     < NN;
        bool vB1 = (c0 + 2*hm1 + 1) < NN;
        const uint2* p1 = (const uint2*)(h3 + ((size_t)b*NN + c0 + 2*hm1)*F3 + 4*hj1);
        uint2 hA1 = vA1 ? p1[0]  : (uint2){0u,0u};
        uint2 hB1 = vB1 ? p1[12] : (uint2){0u,0u};
        unsigned e0 = (hA1.x & 0xFFFFu) | (hB1.x << 16);
        unsigned e1 = (hA1.x >> 16)     | (hB1.x & 0xFFFF0000u);
        unsigned e2 = (hA1.y & 0xFFFFu) | (hB1.y << 16);
        unsigned e3 = (hA1.y >> 16)     | (hB1.y & 0xFFFF0000u);
        #pragma unroll
        for (int i2=0; i2<4; i2++){
          int f = 4*hj1 + i2;
          int col = hm1 ^ (((f>>4)&3)<<3);
          unsigned dv = (i2==0)?e0:(i2==1)?e1:(i2==2)?e2:e3;
          smemS[HTO + f*36 + col] = dv;
        }
      }
    }
  };

  auto mfma_phase = [&](){
    int pr = (ks<<4) + ((l>>4)<<2);
    s8v Af[3], Al[3], Bf[3];
    #pragma unroll
    for (int mt=0; mt<3; mt++) if (mt < mtcnt){
      int row = (mtoff+mt)*16 + (l&15);
      int col = pr ^ (((row>>4)&3)<<3);
      Af[mt] = *(const s8v*)&smemS[row*36 + col];
      Al[mt] = *(const s8v*)&smemS[SLO + row*36 + col];
    }
    #pragma unroll
    for (int bt=0; bt<3; bt++){
      int f = bt*16 + (l&15);
      int col = pr ^ (((f>>4)&3)<<3);
      Bf[bt] = *(const s8v*)&smemS[HTO + f*36 + col];
    }
    #pragma unroll
    for (int mt=0; mt<3; mt++) if (mt < mtcnt)
      #pragma unroll
      for (int bt=0; bt<3; bt++){
        acc[mt][bt] = __builtin_amdgcn_mfma_f32_16x16x32_bf16(Af[mt], Bf[bt], acc[mt][bt], 0, 0, 0);
        acc[mt][bt] = __builtin_amdgcn_mfma_f32_16x16x32_bf16(Al[mt], Bf[bt], acc[mt][bt], 0, 0, 0);
      }
  };

  consume_pack(0);
  SYNC_LDS();

  for (int c = 0; c < 13; c++){
    mfma_phase();
    if (c < 12){
      SYNC_LDS();
      consume_pack(c+1);
      SYNC_LDS();
    }
  }

  __syncthreads();
  float* cred = (float*)&smemS[0];
  if (ks == 0){
    #pragma unroll
    for (int mt=0; mt<3; mt++) if (mt < mtcnt)
      #pragma unroll
      for (int bt=0; bt<3; bt++)
        #pragma unroll
        for (int r=0; r<4; r++){
          int row = (mtoff+mt)*16 + (l>>4)*4 + r;
          int col = bt*16 + (l&15);
          cred[row*49 + col] = acc[mt][bt][r];
        }
  }
  __syncthreads();
  if (ks == 1){
    #pragma unroll
    for (int mt=0; mt<3; mt++) if (mt < mtcnt)
      #pragma unroll
      for (int bt=0; bt<3; bt++)
        #pragma unroll
        for (int r=0; r<4; r++){
          int row = (mtoff+mt)*16 + (l>>4)*4 + r;
          int col = bt*16 + (l&15);
          cred[row*49 + col] += acc[mt][bt][r];
        }
  }
  __syncthreads();
  for (int t = tid; t < KK*F3; t += 256){
    int r = t / F3, c2 = t - r*F3;
    g[(size_t)b*(KK*F3) + t] = cred[r*49 + c2];
  }
}

// Register-prefetch dense: out = act(A @ W + b). ACT: 0=relu,1=sigmoid,2=partial.
template<int ACT>
__global__ __launch_bounds__(256)
void dense_kernel(const float* __restrict__ A, const float* __restrict__ W,
                  const float* __restrict__ bias, float* __restrict__ out,
                  int M, int K, int Nn, int kChunk){
  __shared__ float As[16][65];
  __shared__ float Bs[16][64];
  int tx = threadIdx.x & 15, ty = threadIdx.x >> 4;
  int m0 = blockIdx.x*64, n0 = blockIdx.y*64;
  int ks = blockIdx.z * kChunk;
  int ke = min(K, ks + kChunk);
  int a_kk = threadIdx.x & 15, a_mm = threadIdx.x >> 4;
  int b_nn = threadIdx.x & 63, b_k0 = threadIdx.x >> 6;
  float ra[4], rb[4];
  float acc[4][4] = {};

  #pragma unroll
  for (int s=0; s<4; s++){
    int gk = ks + a_kk;
    ra[s] = (gk < ke) ? A[(size_t)(m0 + a_mm + s*16)*K + gk] : 0.f;
  }
  #pragma unroll
  for (int s=0; s<4; s++){
    int gk = ks + b_k0 + s*4, gn = n0 + b_nn;
    rb[s] = (gk < ke && gn < Nn) ? W[(size_t)gk*Nn + gn] : 0.f;
  }

  for (int k0 = ks; k0 < ke; k0 += 16){
    #pragma unroll
    for (int s=0; s<4; s++) As[a_kk][a_mm + s*16] = ra[s];
    #pragma unroll
    for (int s=0; s<4; s++) Bs[b_k0 + s*4][b_nn] = rb[s];
    __syncthreads();
    if (k0 + 16 < ke){
      #pragma unroll
      for (int s=0; s<4; s++){
        int gk = k0 + 16 + a_kk;
        ra[s] = (gk < ke) ? A[(size_t)(m0 + a_mm + s*16)*K + gk] : 0.f;
      }
      #pragma unroll
      for (int s=0; s<4; s++){
        int gk = k0 + 16 + b_k0 + s*4, gn = n0 + b_nn;
        rb[s] = (gk < ke && gn < Nn) ? W[(size_t)gk*Nn + gn] : 0.f;
      }
    }
    #pragma unroll
    for (int kk=0; kk<16; kk++){
      float a[4], bv[4];
      #pragma unroll
      for (int i2=0; i2<4; i2++) a[i2] = As[kk][ty*4+i2];
      #pragma unroll
      for (int j2=0; j2<4; j2++) bv[j2] = Bs[kk][tx*4+j2];
      #pragma unroll
      for (int i2=0; i2<4; i2++)
        #pragma unroll
        for (int j2=0; j2<4; j2++) acc[i2][j2] += a[i2]*bv[j2];
    }
    __syncthreads();
  }

  if (ACT == 2){
    float* po = out + (size_t)blockIdx.z*M*Nn;
    #pragma unroll
    for (int j2=0; j2<4; j2++){
      int gn = n0 + tx*4 + j2;
      if (gn < Nn){
        #pragma unroll
        for (int i2=0; i2<4; i2++)
          po[(size_t)(m0 + ty*4 + i2)*Nn + gn] = acc[i2][j2];
      }
    }
  } else {
    #pragma unroll
    for (int j2=0; j2<4; j2++){
      int gn = n0 + tx*4 + j2;
      if (gn < Nn){
        float bb = bias[gn];
        #pragma unroll
        for (int i2=0; i2<4; i2++){
          float v = acc[i2][j2] + bb;
          v = (ACT == 0) ? fmaxf(v, 0.f) : 1.0f/(1.0f + __expf(-v));
          out[(size_t)(m0 + ty*4 + i2)*Nn + gn] = v;
        }
      }
    }
  }
}

// dual-B partial: B column gn<70 from Wmu, else Wvar
__global__ __launch_bounds__(256)
void dense_dualB_partial(const float* __restrict__ A, const float* __restrict__ Wmu,
                         const float* __restrict__ Wvar, float* __restrict__ out,
                         int M, int K, int Nn, int kChunk){
  __shared__ float As[16][65];
  __shared__ float Bs[16][64];
  int tx = threadIdx.x & 15, ty = threadIdx.x >> 4;
  int m0 = blockIdx.x*64, n0 = blockIdx.y*64;
  int ks = blockIdx.z * kChunk;
  int ke = min(K, ks + kChunk);
  int a_kk = threadIdx.x & 15, a_mm = threadIdx.x >> 4;
  int b_nn = threadIdx.x & 63, b_k0 = threadIdx.x >> 6;
  float ra[4], rb[4];
  float acc[4][4] = {};

  auto bload = [&](int gk, int gn)->float{
    if (gk >= ke || gn >= Nn) return 0.f;
    return (gn < ZD) ? Wmu[(size_t)gk*ZD + gn] : Wvar[(size_t)gk*ZD + gn - ZD];
  };

  #pragma unroll
  for (int s=0; s<4; s++){
    int gk = ks + a_kk;
    ra[s] = (gk < ke) ? A[(size_t)(m0 + a_mm + s*16)*K + gk] : 0.f;
  }
  #pragma unroll
  for (int s=0; s<4; s++) rb[s] = bload(ks + b_k0 + s*4, n0 + b_nn);

  for (int k0 = ks; k0 < ke; k0 += 16){
    #pragma unroll
    for (int s=0; s<4; s++) As[a_kk][a_mm + s*16] = ra[s];
    #pragma unroll
    for (int s=0; s<4; s++) Bs[b_k0 + s*4][b_nn] = rb[s];
    __syncthreads();
    if (k0 + 16 < ke){
      #pragma unroll
      for (int s=0; s<4; s++){
        int gk = k0 + 16 + a_kk;
        ra[s] = (gk < ke) ? A[(size_t)(m0 + a_mm + s*16)*K + gk] : 0.f;
      }
      #pragma unroll
      for (int s=0; s<4; s++) rb[s] = bload(k0 + 16 + b_k0 + s*4, n0 + b_nn);
    }
    #pragma unroll
    for (int kk=0; kk<16; kk++){
      float a[4], bv[4];
      #pragma unroll
      for (int i2=0; i2<4; i2++) a[i2] = As[kk][ty*4+i2];
      #pragma unroll
      for (int j2=0; j2<4; j2++) bv[j2] = Bs[kk][tx*4+j2];
      #pragma unroll
      for (int i2=0; i2<4; i2++)
        #pragma unroll
        for (int j2=0; j2<4; j2++) acc[i2][j2] += a[i2]*bv[j2];
    }
    __syncthreads();
  }

  float* po = out + (size_t)blockIdx.z*M*Nn;
  #pragma unroll
  for (int j2=0; j2<4; j2++){
    int gn = n0 + tx*4 + j2;
    if (gn < Nn){
      #pragma unroll
      for (int i2=0; i2<4; i2++)
        po[(size_t)(m0 + ty*4 + i2)*Nn + gn] = acc[i2][j2];
    }
  }
}

// split-K partial reduction + bias + activation (0=relu, 1=sigmoid)
template<int ACT>
__global__ __launch_bounds__(256)
void reduce_bias_act(const float* __restrict__ part, const float* __restrict__ bias,
                     float* __restrict__ out, int M, int Nn, int S){
  int idx = blockIdx.x*256 + threadIdx.x;
  if (idx >= M*Nn) return;
  int n = idx % Nn;
  float s = bias[n];
  for (int i=0; i<S; i++) s += part[(size_t)i*M*Nn + idx];
  out[idx] = (ACT == 0) ? fmaxf(s, 0.f) : 1.0f/(1.0f + __expf(-s));
}

// reduce mu|var partials + reparameterize
__global__ __launch_bounds__(256)
void reduce_reparam(const float* __restrict__ part, const float* __restrict__ bmu,
                    const float* __restrict__ bvar, const float* __restrict__ eps,
                    float* __restrict__ z, int S){
  int idx = blockIdx.x*256 + threadIdx.x;
  int b = idx / ZD, zi = idx - b*ZD;
  float mu = bmu[zi], va = bvar[zi];
  for (int s=0; s<S; s++){
    const float* pr = part + ((size_t)s*BB + b)*140;
    mu += pr[zi];
    va += pr[ZD + zi];
  }
  float sp = fmaxf(va, 0.f) + log1pf(__expf(-fabsf(va)));
  z[idx] = mu + eps[idx]*sqrtf(sp + 1e-10f);
}

extern "C" void kernel_launch(void* const* d_in, const int* in_sizes, int n_in,
                              void* d_out, int out_size, void* d_ws, size_t ws_size,
                              hipStream_t stream){
  (void)in_sizes; (void)n_in; (void)out_size; (void)ws_size;
  const float* nodes  = (const float*)d_in[0];
  const float* logits = (const float*)d_in[1];
  const float* gumbel = (const float*)d_in[2];
  const float* eps    = (const float*)d_in[3];
  const float* W1 =(const float*)d_in[4],  *b1 =(const float*)d_in[5];
  const float* W2 =(const float*)d_in[6],  *b2 =(const float*)d_in[7];
  const float* W3 =(const float*)d_in[8],  *b3 =(const float*)d_in[9];
  const float* We1=(const float*)d_in[10], *be1=(const float*)d_in[11];
  const float* We2=(const float*)d_in[12], *be2=(const float*)d_in[13];
  const float* Wmu=(const float*)d_in[14], *bmu=(const float*)d_in[15];
  const float* Wvr=(const float*)d_in[16], *bvr=(const float*)d_in[17];
  const float* Wd1=(const float*)d_in[18], *bd1=(const float*)d_in[19];
  const float* Wd2=(const float*)d_in[20], *bd2=(const float*)d_in[21];

  char* ws = (char*)d_ws;
  bf16*  h3 = (bf16*)(ws);                 // 77,070,336 B
  float* g  = (float*)(ws + 77070336);     // 13,762,560 B
  float* e1 = (float*)(ws + 90832896);
  float* e2 = (float*)(ws + 92471296);
  float* zb = (float*)(ws + 94109696);
  float* dd = (float*)(ws + 94396416);
  float* part = (float*)(ws);              // aliases h3 (dead after einsum)
  float* out = (float*)d_out;

  gcn_fused<<<4096, 256, 0, stream>>>(nodes, W1, b1, W2, b2, W3, b3, h3);
  einsum_mfma_kernel<<<1024, 256, 0, stream>>>(logits, gumbel, h3, g);
  dense_kernel<2><<<dim3(16, 7, 8), 256, 0, stream>>>(g, We1, nullptr, part, 1024, 3360, 400, 432);
  reduce_bias_act<0><<<1600, 256, 0, stream>>>(part, be1, e1, 1024, 400, 8);
  dense_kernel<2><<<dim3(16, 7, 4), 256, 0, stream>>>(e1, We2, nullptr, part, 1024, 400, 400, 112);
  reduce_bias_act<0><<<1600, 256, 0, stream>>>(part, be2, e2, 1024, 400, 4);
  dense_dualB_partial<<<dim3(16, 3, 4), 256, 0, stream>>>(e2, Wmu, Wvr, part, 1024, 400, 140, 112);
  reduce_reparam<<<280, 256, 0, stream>>>(part, bmu, bvr, eps, zb, 4);
  dense_kernel<0><<<dim3(16, 7, 1), 256, 0, stream>>>(zb, Wd1, bd1, dd, 1024, 70, 400, 70);
  dense_kernel<2><<<dim3(16, 13, 4), 256, 0, stream>>>(dd, Wd2, nullptr, part, 1024, 400, 784, 112);
  reduce_bias_act<1><<<3136, 256, 0, stream>>>(part, bd2, out, 1024, 784, 4);
}

// Round 19
// 395.433 us; speedup vs baseline: 1.9399x; 1.0123x over previous
//
#include <hip/hip_runtime.h>
#include <hip/hip_bf16.h>

// VAE with grid-GCN encoder, MI355X. Round 18: einsum single-precision bf16 A
// (drop hi/lo split): LDS 30.2->18.4KB => 8 blocks/CU (2x concurrency),
// MFMA count halved, pack VALU -35%. gcn + dense chain unchanged (r15).

#define BB 1024
#define HG 28
#define NN 784
#define KK 70
#define F3 48
#define HD 400
#define ZD 70
#define IMGD 784

typedef __hip_bfloat16 bf16;
typedef __attribute__((ext_vector_type(8))) short s8v;
typedef __attribute__((ext_vector_type(4))) float f32x4;

__device__ __forceinline__ float dinv_ij(int i, int j){
  int deg = 1 + (i>0) + (i<HG-1) + (j>0) + (j<HG-1);
  return rsqrtf((float)deg);
}

__device__ __forceinline__ unsigned pk2(float a, float b){
  union { bf16 h; unsigned short u; } ua, ub;
  ua.h = __float2bfloat16(a); ub.h = __float2bfloat16(b);
  return ((unsigned)ub.u << 16) | ua.u;
}

__device__ __forceinline__ short bfbits(float v){
  union { bf16 h; short s; } u; u.h = __float2bfloat16(v); return u.s;
}

// LDS-visibility barrier WITHOUT vmcnt drain.
#define SYNC_LDS() do {                                   \
    asm volatile("" ::: "memory");                        \
    asm volatile("s_waitcnt lgkmcnt(0)" ::: "memory");    \
    __builtin_amdgcn_s_barrier();                         \
    asm volatile("" ::: "memory");                        \
  } while(0)

// Three GCN layers fused, one block per (sample, 7-row slab). (unchanged)
__global__ __launch_bounds__(256, 2)
void gcn_fused(const float* __restrict__ nodes,
               const float* __restrict__ W1, const float* __restrict__ b1,
               const float* __restrict__ W2, const float* __restrict__ b2,
               const float* __restrict__ W3, const float* __restrict__ b3,
               bf16* __restrict__ h3){
  __shared__ __align__(16) char smem[73216];
  float* regA = (float*)smem;
  float* regB = (float*)(smem + 36288);
  float* wbuf = (float*)(smem + 64512);
  float* W1s = wbuf;          float* b1s = wbuf + 32;
  float* W2s = wbuf + 48;     float* b2s = wbuf + 560;
  float* W3s = wbuf + 592;    float* b3s = wbuf + 2128;

  int tid = threadIdx.x;
  if (tid < 32)  W1s[tid] = W1[tid];
  if (tid < 16)  b1s[tid] = b1[tid];
  for (int t = tid; t < 512;  t += 256) W2s[t] = W2[t];
  if (tid < 32)  b2s[tid] = b2[tid];
  for (int t = tid; t < 1536; t += 256) W3s[t] = W3[t];
  if (tid < 48)  b3s[tid] = b3[tid];

  int b = blockIdx.x >> 2, s = blockIdx.x & 3;
  int base3 = s*7;
  int base2 = base3 - 1;
  int base1 = base3 - 2;
  const float* nb = nodes + (size_t)b*NN*2;
  __syncthreads();

  // P1: layer 1 -> h1s[308][20]
  {
    float* h1s = regA;
    for (int t = tid; t < 308; t += 256){
      int lr = t/28, j = t - lr*28;
      int r = base1 + lr;
      float o[16] __attribute__((aligned(16)));
      if (r < 0 || r >= HG){
        #pragma unroll
        for (int f=0; f<16; f++) o[f] = 0.f;
      } else {
        float dn = dinv_ij(r,j);
        float a0 = dn*nb[(r*HG+j)*2+0], a1 = dn*nb[(r*HG+j)*2+1];
        if (r > 0)   { float w=dinv_ij(r-1,j); a0 += w*nb[((r-1)*HG+j)*2]; a1 += w*nb[((r-1)*HG+j)*2+1]; }
        if (r < HG-1){ float w=dinv_ij(r+1,j); a0 += w*nb[((r+1)*HG+j)*2]; a1 += w*nb[((r+1)*HG+j)*2+1]; }
        if (j > 0)   { float w=dinv_ij(r,j-1); a0 += w*nb[(r*HG+j-1)*2];   a1 += w*nb[(r*HG+j-1)*2+1]; }
        if (j < HG-1){ float w=dinv_ij(r,j+1); a0 += w*nb[(r*HG+j+1)*2];   a1 += w*nb[(r*HG+j+1)*2+1]; }
        a0 *= dn; a1 *= dn;
        #pragma unroll
        for (int f=0; f<16; f++) o[f] = fmaxf(a0*W1s[f] + a1*W1s[16+f] + b1s[f], 0.f);
      }
      float* dst = h1s + t*20;
      #pragma unroll
      for (int qq=0; qq<4; qq++) *(float4*)(dst + 4*qq) = *(float4*)&o[4*qq];
    }
  }
  __syncthreads();

  // P2: agg1[252][20]
  if (tid < 252){
    const float* h1s = regA;
    float* agg1 = regB;
    int lr = tid/28, j = tid - lr*28;
    int r = base2 + lr;
    float o[16] __attribute__((aligned(16)));
    if (r < 0 || r >= HG){
      #pragma unroll
      for (int f=0; f<16; f++) o[f] = 0.f;
    } else {
      int ln = (lr+1)*28 + j;
      float dn = dinv_ij(r,j);
      float wu = dinv_ij(r-1,j), wd = dinv_ij(r+1,j);
      float wl = (j>0)    ? dinv_ij(r,j-1) : 0.f;
      float wr = (j<HG-1) ? dinv_ij(r,j+1) : 0.f;
      const float* pc = h1s + ln*20;
      #pragma unroll
      for (int qq=0; qq<4; qq++){
        float4 vc = *(const float4*)(pc + 4*qq);
        float4 vu = *(const float4*)(pc - 28*20 + 4*qq);
        float4 vd = *(const float4*)(pc + 28*20 + 4*qq);
        float4 vl = *(const float4*)(pc - 20 + 4*qq);
        float4 vr = *(const float4*)(pc + 20 + 4*qq);
        o[4*qq+0] = dn*(dn*vc.x + wu*vu.x + wd*vd.x + wl*vl.x + wr*vr.x);
        o[4*qq+1] = dn*(dn*vc.y + wu*vu.y + wd*vd.y + wl*vl.y + wr*vr.y);
        o[4*qq+2] = dn*(dn*vc.z + wu*vu.z + wd*vd.z + wl*vl.z + wr*vr.z);
        o[4*qq+3] = dn*(dn*vc.w + wu*vu.w + wd*vd.w + wl*vl.w + wr*vr.w);
      }
    }
    float* dst = agg1 + tid*20;
    #pragma unroll
    for (int qq=0; qq<4; qq++) *(float4*)(dst + 4*qq) = *(float4*)&o[4*qq];
  }
  __syncthreads();

  // P3: L2-GEMM h2s[252][36]
  {
    const float* agg1 = regB;
    float* h2s = regA;
    int tx = tid & 7, ty = tid >> 3;
    float4 w2r[16];
    #pragma unroll
    for (int fi=0; fi<16; fi++) w2r[fi] = *(const float4*)&W2s[fi*32 + tx*4];
    float4 bb = *(const float4*)&b2s[tx*4];
    #pragma unroll
    for (int i=0; i<8; i++){
      int n = ty + 32*i;
      if (n < 252){
        float af[16] __attribute__((aligned(16)));
        const float* ap = agg1 + n*20;
        #pragma unroll
        for (int qq=0; qq<4; qq++) *(float4*)&af[4*qq] = *(const float4*)(ap + 4*qq);
        float4 acc = bb;
        #pragma unroll
        for (int fi=0; fi<16; fi++){
          float a = af[fi];
          acc.x += a*w2r[fi].x; acc.y += a*w2r[fi].y;
          acc.z += a*w2r[fi].z; acc.w += a*w2r[fi].w;
        }
        acc.x = fmaxf(acc.x,0.f); acc.y = fmaxf(acc.y,0.f);
        acc.z = fmaxf(acc.z,0.f); acc.w = fmaxf(acc.w,0.f);
        *(float4*)&h2s[n*36 + tx*4] = acc;
      }
    }
  }
  __syncthreads();

  // P4: agg2[196][36]
  if (tid < 196){
    const float* h2s = regA;
    float* agg2 = regB;
    int lr = tid/28, j = tid - lr*28;
    int r = base3 + lr;
    int ln = (lr+1)*28 + j;
    float dn = dinv_ij(r,j);
    float wu = dinv_ij(r-1,j), wd = dinv_ij(r+1,j);
    float wl = (j>0)    ? dinv_ij(r,j-1) : 0.f;
    float wr = (j<HG-1) ? dinv_ij(r,j+1) : 0.f;
    const float* pc = h2s + ln*36;
    float* dst = agg2 + tid*36;
    #pragma unroll
    for (int qq=0; qq<8; qq++){
      float4 vc = *(const float4*)(pc + 4*qq);
      float4 vu = *(const float4*)(pc - 28*36 + 4*qq);
      float4 vd = *(const float4*)(pc + 28*36 + 4*qq);
      float4 vl = *(const float4*)(pc - 36 + 4*qq);
      float4 vr = *(const float4*)(pc + 36 + 4*qq);
      float4 o;
      o.x = dn*(dn*vc.x + wu*vu.x + wd*vd.x + wl*vl.x + wr*vr.x);
      o.y = dn*(dn*vc.y + wu*vu.y + wd*vd.y + wl*vl.y + wr*vr.y);
      o.z = dn*(dn*vc.z + wu*vu.z + wd*vd.z + wl*vl.z + wr*vr.z);
      o.w = dn*(dn*vc.w + wu*vu.w + wd*vd.w + wl*vl.w + wr*vr.w);
      *(float4*)(dst + 4*qq) = o;
    }
  }
  __syncthreads();

  // P5: L3-GEMM h3buf[196][56]bf16
  {
    bf16* h3buf = (bf16*)regA;
    if (tid < 252){
      const float* agg2 = regB;
      int tx = tid % 12, ty = tid / 12;
      float4 w3r[32];
      #pragma unroll
      for (int fi=0; fi<32; fi++) w3r[fi] = *(const float4*)&W3s[fi*48 + tx*4];
      float4 bb = *(const float4*)&b3s[tx*4];
      #pragma unroll
      for (int i=0; i<10; i++){
        int n = ty + 21*i;
        if (n < 196){
          float af[32] __attribute__((aligned(16)));
          const float* ap = agg2 + n*36;
          #pragma unroll
          for (int qq=0; qq<8; qq++) *(float4*)&af[4*qq] = *(const float4*)(ap + 4*qq);
          float4 acc = bb;
          #pragma unroll
          for (int fi=0; fi<32; fi++){
            float a = af[fi];
            acc.x += a*w3r[fi].x; acc.y += a*w3r[fi].y;
            acc.z += a*w3r[fi].z; acc.w += a*w3r[fi].w;
          }
          uint2 pv;
          pv.x = pk2(fmaxf(acc.x,0.f), fmaxf(acc.y,0.f));
          pv.y = pk2(fmaxf(acc.z,0.f), fmaxf(acc.w,0.f));
          *(uint2*)((char*)h3buf + n*112 + tx*8) = pv;
        }
      }
    }
  }
  __syncthreads();

  // P6: coalesced copyout
  {
    const char* h3buf = (const char*)regA;
    uint4* dst = (uint4*)(h3 + ((size_t)b*NN + base3*28)*F3);
    for (int t = tid; t < 1176; t += 256){
      int n = t/6, gq = t - n*6;
      dst[t] = *(const uint4*)(h3buf + n*112 + gq*16);
    }
  }
}

// Gumbel-softmax + einsum via MFMA, single-precision bf16 A operand.
// LDS 18,432 B (dh[80][36] | ht[48][36]) -> 8 blocks/CU.
__global__
void einsum_mfma_kernel(const float* __restrict__ logits, const float* __restrict__ gumbel,
                        const bf16* __restrict__ h3, float* __restrict__ g){
  __shared__ __align__(16) unsigned smemS[4608];   // dh[80][36] | ht[48][36]
  const int HTO = 2880;

  int b = blockIdx.x, tid = threadIdx.x;
  int l = tid & 63, w = tid >> 6;
  int n_loc = tid >> 2, q = tid & 3;
  int kstart = q << 4;
  int kcnt = (q < 3) ? 16 : 22;
  int kc2 = kcnt >> 1;
  int m_pair = tid >> 3;
  int half = (tid >> 2) & 1;
  int ks = w >> 1, mh = w & 1;
  int mtoff = mh ? 3 : 0, mtcnt = mh ? 2 : 3;

  // zero k-rows 70..79 of dh (read by the 5th m-tile; never written otherwise)
  for (int t = tid; t < 360; t += 256) smemS[2520 + t] = 0u;

  f32x4 acc[3][3];
  #pragma unroll
  for (int mt=0; mt<3; mt++)
    #pragma unroll
    for (int bt=0; bt<3; bt++) acc[mt][bt] = (f32x4){0.f,0.f,0.f,0.f};

  int hm0 = tid/12, hj0 = tid - hm0*12;
  int tt1 = tid + 256;
  int hm1 = tt1/12, hj1 = tt1 - hm1*12;

  auto consume_pack = [&](int c){
    int c0 = c << 6;
    int node = c0 + n_loc;
    bool v = node < NN;
    const float* lp = logits + ((size_t)b*NN + node)*KK + kstart;
    const float* gp = gumbel + ((size_t)b*NN + node)*KK + kstart;
    int nld = (q < 3) ? 8 : 11;
    float x[22];
    #pragma unroll
    for (int s=0; s<11; s++){
      bool a = v && (s < nld);
      float2 lv = a ? *(const float2*)(lp + 2*s) : (float2){0.f,0.f};
      float2 gv = a ? *(const float2*)(gp + 2*s) : (float2){0.f,0.f};
      x[2*s]   = 2.f*(lv.x + gv.x);
      x[2*s+1] = 2.f*(lv.y + gv.y);
    }
    float mx = -1e30f;
    #pragma unroll
    for (int i=0; i<22; i++) if (i < kcnt) mx = fmaxf(mx, x[i]);
    mx = fmaxf(mx, __shfl_xor(mx, 1));
    mx = fmaxf(mx, __shfl_xor(mx, 2));
    float sum = 0.f;
    #pragma unroll
    for (int i=0; i<22; i++) if (i < kcnt){ x[i] = __expf(x[i]-mx); sum += x[i]; }
    sum += __shfl_xor(sum, 1);
    sum += __shfl_xor(sum, 2);
    float rs = v ? 1.0f/sum : 0.f;
    #pragma unroll
    for (int i=0; i<22; i++){
      if (i < kcnt){
        float p = x[i]*rs;
        unsigned hb = (unsigned)(unsigned short)bfbits(p);
        unsigned phb = (unsigned)__shfl_xor((int)hb, 4);
        unsigned dh = (half==0) ? (hb | (phb<<16)) : (phb | (hb<<16));
        bool doW = (half==0) ? (i < kc2) : (i >= kc2);
        if (doW){
          int k = kstart + i;
          int col = m_pair ^ (((k>>4)&3)<<3);
          smemS[k*36 + col] = dh;
        }
      }
    }
    {
      bool vA0 = (c0 + 2*hm0)     < NN;
      bool vB0 = (c0 + 2*hm0 + 1) < NN;
      const uint2* p0 = (const uint2*)(h3 + ((size_t)b*NN + c0 + 2*hm0)*F3 + 4*hj0);
      uint2 hA0 = vA0 ? p0[0]  : (uint2){0u,0u};
      uint2 hB0 = vB0 ? p0[12] : (uint2){0u,0u};
      unsigned d0 = (hA0.x & 0xFFFFu) | (hB0.x << 16);
      unsigned d1 = (hA0.x >> 16)     | (hB0.x & 0xFFFF0000u);
      unsigned d2 = (hA0.y & 0xFFFFu) | (hB0.y << 16);
      unsigned d3 = (hA0.y >> 16)     | (hB0.y & 0xFFFF0000u);
      #pragma unroll
      for (int i2=0; i2<4; i2++){
        int f = 4*hj0 + i2;
        int col = hm0 ^ (((f>>4)&3)<<3);
        unsigned dv = (i2==0)?d0:(i2==1)?d1:(i2==2)?d2:d3;
        smemS[HTO + f*36 + col] = dv;
      }
      if (tid < 128){
        bool vA1 = (c0 + 2*hm1)     < NN;
        bool vB1 = (c0 + 2*hm1 + 1) < NN;
        const uint2* p1 = (const uint2*)(h3 + ((size_t)b*NN + c0 + 2*hm1)*F3 + 4*hj1);
        uint2 hA1 = vA1 ? p1[0]  : (uint2){0u,0u};
        uint2 hB1 = vB1 ? p1[12] : (uint2){0u,0u};
        unsigned e0 = (hA1.x & 0xFFFFu) | (hB1.x << 16);
        unsigned e1 = (hA1.x >> 16)     | (hB1.x & 0xFFFF0000u);
        unsigned e2 = (hA1.y & 0xFFFFu) | (hB1.y << 16);
        unsigned e3 = (hA1.y >> 16)     | (hB1.y & 0xFFFF0000u);
        #pragma unroll
        for (int i2=0; i2<4; i2++){
          int f = 4*hj1 + i2;
          int col = hm1 ^ (((f>>4)&3)<<3);
          unsigned dv = (i2==0)?e0:(i2==1)?e1:(i2==2)?e2:e3;
          smemS[HTO + f*36 + col] = dv;
        }
      }
    }
  };

  auto mfma_phase = [&](){
    int pr = (ks<<4) + ((l>>4)<<2);
    s8v Af[3], Bf[3];
    #pragma unroll
    for (int mt=0; mt<3; mt++) if (mt < mtcnt){
      int row = (mtoff+mt)*16 + (l&15);
      int col = pr ^ (((row>>4)&3)<<3);
      Af[mt] = *(const s8v*)&smemS[row*36 + col];
    }
    #pragma unroll
    for (int bt=0; bt<3; bt++){
      int f = bt*16 + (l&15);
      int col = pr ^ (((f>>4)&3)<<3);
      Bf[bt] = *(const s8v*)&smemS[HTO + f*36 + col];
    }
    #pragma unroll
    for (int mt=0; mt<3; mt++) if (mt < mtcnt)
      #pragma unroll
      for (int bt=0; bt<3; bt++)
        acc[mt][bt] = __builtin_amdgcn_mfma_f32_16x16x32_bf16(Af[mt], Bf[bt], acc[mt][bt], 0, 0, 0);
  };

  consume_pack(0);
  SYNC_LDS();

  for (int c = 0; c < 13; c++){
    mfma_phase();
    if (c < 12){
      SYNC_LDS();
      consume_pack(c+1);
      SYNC_LDS();
    }
  }

  __syncthreads();
  float* cred = (float*)&smemS[0];
  if (ks == 0){
    #pragma unroll
    for (int mt=0; mt<3; mt++) if (mt < mtcnt)
      #pragma unroll
      for (int bt=0; bt<3; bt++)
        #pragma unroll
        for (int r=0; r<4; r++){
          int row = (mtoff+mt)*16 + (l>>4)*4 + r;
          int col = bt*16 + (l&15);
          cred[row*49 + col] = acc[mt][bt][r];
        }
  }
  __syncthreads();
  if (ks == 1){
    #pragma unroll
    for (int mt=0; mt<3; mt++) if (mt < mtcnt)
      #pragma unroll
      for (int bt=0; bt<3; bt++)
        #pragma unroll
        for (int r=0; r<4; r++){
          int row = (mtoff+mt)*16 + (l>>4)*4 + r;
          int col = bt*16 + (l&15);
          cred[row*49 + col] += acc[mt][bt][r];
        }
  }
  __syncthreads();
  for (int t = tid; t < KK*F3; t += 256){
    int r = t / F3, c2 = t - r*F3;
    g[(size_t)b*(KK*F3) + t] = cred[r*49 + c2];
  }
}

// Register-prefetch dense: out = act(A @ W + b). ACT: 0=relu,1=sigmoid,2=partial.
template<int ACT>
__global__ __launch_bounds__(256)
void dense_kernel(const float* __restrict__ A, const float* __restrict__ W,
                  const float* __restrict__ bias, float* __restrict__ out,
                  int M, int K, int Nn, int kChunk){
  __shared__ float As[16][65];
  __shared__ float Bs[16][64];
  int tx = threadIdx.x & 15, ty = threadIdx.x >> 4;
  int m0 = blockIdx.x*64, n0 = blockIdx.y*64;
  int ks = blockIdx.z * kChunk;
  int ke = min(K, ks + kChunk);
  int a_kk = threadIdx.x & 15, a_mm = threadIdx.x >> 4;
  int b_nn = threadIdx.x & 63, b_k0 = threadIdx.x >> 6;
  float ra[4], rb[4];
  float acc[4][4] = {};

  #pragma unroll
  for (int s=0; s<4; s++){
    int gk = ks + a_kk;
    ra[s] = (gk < ke) ? A[(size_t)(m0 + a_mm + s*16)*K + gk] : 0.f;
  }
  #pragma unroll
  for (int s=0; s<4; s++){
    int gk = ks + b_k0 + s*4, gn = n0 + b_nn;
    rb[s] = (gk < ke && gn < Nn) ? W[(size_t)gk*Nn + gn] : 0.f;
  }

  for (int k0 = ks; k0 < ke; k0 += 16){
    #pragma unroll
    for (int s=0; s<4; s++) As[a_kk][a_mm + s*16] = ra[s];
    #pragma unroll
    for (int s=0; s<4; s++) Bs[b_k0 + s*4][b_nn] = rb[s];
    __syncthreads();
    if (k0 + 16 < ke){
      #pragma unroll
      for (int s=0; s<4; s++){
        int gk = k0 + 16 + a_kk;
        ra[s] = (gk < ke) ? A[(size_t)(m0 + a_mm + s*16)*K + gk] : 0.f;
      }
      #pragma unroll
      for (int s=0; s<4; s++){
        int gk = k0 + 16 + b_k0 + s*4, gn = n0 + b_nn;
        rb[s] = (gk < ke && gn < Nn) ? W[(size_t)gk*Nn + gn] : 0.f;
      }
    }
    #pragma unroll
    for (int kk=0; kk<16; kk++){
      float a[4], bv[4];
      #pragma unroll
      for (int i2=0; i2<4; i2++) a[i2] = As[kk][ty*4+i2];
      #pragma unroll
      for (int j2=0; j2<4; j2++) bv[j2] = Bs[kk][tx*4+j2];
      #pragma unroll
      for (int i2=0; i2<4; i2++)
        #pragma unroll
        for (int j2=0; j2<4; j2++) acc[i2][j2] += a[i2]*bv[j2];
    }
    __syncthreads();
  }

  if (ACT == 2){
    float* po = out + (size_t)blockIdx.z*M*Nn;
    #pragma unroll
    for (int j2=0; j2<4; j2++){
      int gn = n0 + tx*4 + j2;
      if (gn < Nn){
        #pragma unroll
        for (int i2=0; i2<4; i2++)
          po[(size_t)(m0 + ty*4 + i2)*Nn + gn] = acc[i2][j2];
      }
    }
  } else {
    #pragma unroll
    for (int j2=0; j2<4; j2++){
      int gn = n0 + tx*4 + j2;
      if (gn < Nn){
        float bb = bias[gn];
        #pragma unroll
        for (int i2=0; i2<4; i2++){
          float v = acc[i2][j2] + bb;
          v = (ACT == 0) ? fmaxf(v, 0.f) : 1.0f/(1.0f + __expf(-v));
          out[(size_t)(m0 + ty*4 + i2)*Nn + gn] = v;
        }
      }
    }
  }
}

// dual-B partial: B column gn<70 from Wmu, else Wvar
__global__ __launch_bounds__(256)
void dense_dualB_partial(const float* __restrict__ A, const float* __restrict__ Wmu,
                         const float* __restrict__ Wvar, float* __restrict__ out,
                         int M, int K, int Nn, int kChunk){
  __shared__ float As[16][65];
  __shared__ float Bs[16][64];
  int tx = threadIdx.x & 15, ty = threadIdx.x >> 4;
  int m0 = blockIdx.x*64, n0 = blockIdx.y*64;
  int ks = blockIdx.z * kChunk;
  int ke = min(K, ks + kChunk);
  int a_kk = threadIdx.x & 15, a_mm = threadIdx.x >> 4;
  int b_nn = threadIdx.x & 63, b_k0 = threadIdx.x >> 6;
  float ra[4], rb[4];
  float acc[4][4] = {};

  auto bload = [&](int gk, int gn)->float{
    if (gk >= ke || gn >= Nn) return 0.f;
    return (gn < ZD) ? Wmu[(size_t)gk*ZD + gn] : Wvar[(size_t)gk*ZD + gn - ZD];
  };

  #pragma unroll
  for (int s=0; s<4; s++){
    int gk = ks + a_kk;
    ra[s] = (gk < ke) ? A[(size_t)(m0 + a_mm + s*16)*K + gk] : 0.f;
  }
  #pragma unroll
  for (int s=0; s<4; s++) rb[s] = bload(ks + b_k0 + s*4, n0 + b_nn);

  for (int k0 = ks; k0 < ke; k0 += 16){
    #pragma unroll
    for (int s=0; s<4; s++) As[a_kk][a_mm + s*16] = ra[s];
    #pragma unroll
    for (int s=0; s<4; s++) Bs[b_k0 + s*4][b_nn] = rb[s];
    __syncthreads();
    if (k0 + 16 < ke){
      #pragma unroll
      for (int s=0; s<4; s++){
        int gk = k0 + 16 + a_kk;
        ra[s] = (gk < ke) ? A[(size_t)(m0 + a_mm + s*16)*K + gk] : 0.f;
      }
      #pragma unroll
      for (int s=0; s<4; s++) rb[s] = bload(k0 + 16 + b_k0 + s*4, n0 + b_nn);
    }
    #pragma unroll
    for (int kk=0; kk<16; kk++){
      float a[4], bv[4];
      #pragma unroll
      for (int i2=0; i2<4; i2++) a[i2] = As[kk][ty*4+i2];
      #pragma unroll
      for (int j2=0; j2<4; j2++) bv[j2] = Bs[kk][tx*4+j2];
      #pragma unroll
      for (int i2=0; i2<4; i2++)
        #pragma unroll
        for (int j2=0; j2<4; j2++) acc[i2][j2] += a[i2]*bv[j2];
    }
    __syncthreads();
  }

  float* po = out + (size_t)blockIdx.z*M*Nn;
  #pragma unroll
  for (int j2=0; j2<4; j2++){
    int gn = n0 + tx*4 + j2;
    if (gn < Nn){
      #pragma unroll
      for (int i2=0; i2<4; i2++)
        po[(size_t)(m0 + ty*4 + i2)*Nn + gn] = acc[i2][j2];
    }
  }
}

// split-K partial reduction + bias + activation (0=relu, 1=sigmoid)
template<int ACT>
__global__ __launch_bounds__(256)
void reduce_bias_act(const float* __restrict__ part, const float* __restrict__ bias,
                     float* __restrict__ out, int M, int Nn, int S){
  int idx = blockIdx.x*256 + threadIdx.x;
  if (idx >= M*Nn) return;
  int n = idx % Nn;
  float s = bias[n];
  for (int i=0; i<S; i++) s += part[(size_t)i*M*Nn + idx];
  out[idx] = (ACT == 0) ? fmaxf(s, 0.f) : 1.0f/(1.0f + __expf(-s));
}

// reduce mu|var partials + reparameterize
__global__ __launch_bounds__(256)
void reduce_reparam(const float* __restrict__ part, const float* __restrict__ bmu,
                    const float* __restrict__ bvar, const float* __restrict__ eps,
                    float* __restrict__ z, int S){
  int idx = blockIdx.x*256 + threadIdx.x;
  int b = idx / ZD, zi = idx - b*ZD;
  float mu = bmu[zi], va = bvar[zi];
  for (int s=0; s<S; s++){
    const float* pr = part + ((size_t)s*BB + b)*140;
    mu += pr[zi];
    va += pr[ZD + zi];
  }
  float sp = fmaxf(va, 0.f) + log1pf(__expf(-fabsf(va)));
  z[idx] = mu + eps[idx]*sqrtf(sp + 1e-10f);
}

extern "C" void kernel_launch(void* const* d_in, const int* in_sizes, int n_in,
                              void* d_out, int out_size, void* d_ws, size_t ws_size,
                              hipStream_t stream){
  (void)in_sizes; (void)n_in; (void)out_size; (void)ws_size;
  const float* nodes  = (const float*)d_in[0];
  const float* logits = (const float*)d_in[1];
  const float* gumbel = (const float*)d_in[2];
  const float* eps    = (const float*)d_in[3];
  const float* W1 =(const float*)d_in[4],  *b1 =(const float*)d_in[5];
  const float* W2 =(const float*)d_in[6],  *b2 =(const float*)d_in[7];
  const float* W3 =(const float*)d_in[8],  *b3 =(const float*)d_in[9];
  const float* We1=(const float*)d_in[10], *be1=(const float*)d_in[11];
  const float* We2=(const float*)d_in[12], *be2=(const float*)d_in[13];
  const float* Wmu=(const float*)d_in[14], *bmu=(const float*)d_in[15];
  const float* Wvr=(const float*)d_in[16], *bvr=(const float*)d_in[17];
  const float* Wd1=(const float*)d_in[18], *bd1=(const float*)d_in[19];
  const float* Wd2=(const float*)d_in[20], *bd2=(const float*)d_in[21];

  char* ws = (char*)d_ws;
  bf16*  h3 = (bf16*)(ws);                 // 77,070,336 B
  float* g  = (float*)(ws + 77070336);     // 13,762,560 B
  float* e1 = (float*)(ws + 90832896);
  float* e2 = (float*)(ws + 92471296);
  float* zb = (float*)(ws + 94109696);
  float* dd = (float*)(ws + 94396416);
  float* part = (float*)(ws);              // aliases h3 (dead after einsum)
  float* out = (float*)d_out;

  gcn_fused<<<4096, 256, 0, stream>>>(nodes, W1, b1, W2, b2, W3, b3, h3);
  einsum_mfma_kernel<<<1024, 256, 0, stream>>>(logits, gumbel, h3, g);
  dense_kernel<2><<<dim3(16, 7, 8), 256, 0, stream>>>(g, We1, nullptr, part, 1024, 3360, 400, 432);
  reduce_bias_act<0><<<1600, 256, 0, stream>>>(part, be1, e1, 1024, 400, 8);
  dense_kernel<2><<<dim3(16, 7, 4), 256, 0, stream>>>(e1, We2, nullptr, part, 1024, 400, 400, 112);
  reduce_bias_act<0><<<1600, 256, 0, stream>>>(part, be2, e2, 1024, 400, 4);
  dense_dualB_partial<<<dim3(16, 3, 4), 256, 0, stream>>>(e2, Wmu, Wvr, part, 1024, 400, 140, 112);
  reduce_reparam<<<280, 256, 0, stream>>>(part, bmu, bvr, eps, zb, 4);
  dense_kernel<0><<<dim3(16, 7, 1), 256, 0, stream>>>(zb, Wd1, bd1, dd, 1024, 70, 400, 70);
  dense_kernel<2><<<dim3(16, 13, 4), 256, 0, stream>>>(dd, Wd2, nullptr, part, 1024, 400, 784, 112);
  reduce_bias_act<1><<<3136, 256, 0, stream>>>(part, bd2, out, 1024, 784, 4);
}